// Round 4
// baseline (767.189 us; speedup 1.0000x reference)
//
#include <hip/hip_runtime.h>
#include <math.h>

#define BQ 4096
#define NMEM 32768
#define DD 512
#define TOPN 10
#define NBX 128                  /* 256-col blocks over NMEM */
#define ENT 2048                 /* candidate entries per row = NBX*16 */
#define NCF 16                   /* final candidates per row */
#define LK 6                     /* per-lane top-K in knn_select scan */
#define FINF 3.402823466e+38f
#define IMAX 0x7fffffff

typedef __attribute__((ext_vector_type(8))) short    bf16x8;
typedef __attribute__((ext_vector_type(4))) float    f32x4;
typedef __attribute__((ext_vector_type(4))) int      i32x4;

// ---------------- helpers ----------------
__device__ __forceinline__ unsigned short f2bf(float x) {
    unsigned int u = __float_as_uint(x);
    u += 0x7fffu + ((u >> 16) & 1u);          // round-to-nearest-even
    return (unsigned short)(u >> 16);
}
__device__ __forceinline__ void async_copy16(const void* gp, void* lp) {
    __builtin_amdgcn_global_load_lds(
        (const __attribute__((address_space(1))) void*)gp,
        (__attribute__((address_space(3))) void*)lp, 16, 0, 0);
}
__device__ __forceinline__ bool lt_si(float s, int j, float s2, int j2) {
    return (s < s2) || (s == s2 && j < j2);   // matches top_k tie-break
}
template<int KN>
__device__ __forceinline__ void topk_insert(float (&ts)[KN], int (&ti)[KN], float s, int j) {
    if (!lt_si(s, j, ts[KN-1], ti[KN-1])) return;
    #pragma unroll
    for (int p = KN-1; p > 0; --p) {
        if (lt_si(s, j, ts[p-1], ti[p-1])) { ts[p] = ts[p-1]; ti[p] = ti[p-1]; }
        else { ts[p] = s; ti[p] = j; return; }
    }
    ts[0] = s; ti[0] = j;
}

// ---------------- segmented cast: visit + 6 weight matrices in ONE dispatch ----------------
struct CastDesc {
    const float* in[7];
    unsigned short* out[7];
    int start[8];   // cumulative block starts, start[7] = total
};
__global__ __launch_bounds__(256) void cast_multi_kernel(CastDesc d) {
    int blk = blockIdx.x;
    int seg = 0;
    #pragma unroll
    for (int s = 0; s < 6; ++s) seg += (blk >= d.start[s + 1]) ? 1 : 0;
    int local = blk - d.start[seg];
    int i = (local * 256 + threadIdx.x) * 4;
    float4 v = *(const float4*)(d.in[seg] + i);
    ushort4 o;
    o.x = f2bf(v.x); o.y = f2bf(v.y); o.z = f2bf(v.z); o.w = f2bf(v.w);
    *(ushort4*)(d.out[seg] + i) = o;
}

// ---------------- fused cast planes over Epat/Emed/visit ----------------
// y==0: Epat -> bf16 + int8(+scale) + ||row||^2 ; y==1: Emed -> bf16 ;
// y==2 (x<1024): visit -> int8(+scale).
// int8 quant: per-row symmetric absmax/127 (d2-error std ~0.5 vs rank
// spacing ~0.45/rank; survivors rescored exact fp32 -> selection-safe).
__global__ __launch_bounds__(256) void cast_norm2_kernel(
        const float* __restrict__ inA, unsigned short* __restrict__ outA,
        const float* __restrict__ inB, unsigned short* __restrict__ outB,
        const float* __restrict__ inV,
        signed char* __restrict__ outA8, signed char* __restrict__ outV8,
        float* __restrict__ mnorm, float* __restrict__ msc,
        float* __restrict__ qsc) {
    const int pl = blockIdx.y;
    if (pl == 2 && blockIdx.x >= BQ / 4) return;
    const float* in = (pl == 0) ? inA : (pl == 1 ? inB : inV);
    int row = blockIdx.x * 4 + (threadIdx.x >> 6);
    int lane = threadIdx.x & 63;
    const float* r = in + (size_t)row * DD + lane * 8;
    float4 a = *(const float4*)r;
    float4 b = *(const float4*)(r + 4);
    if (pl < 2) {
        unsigned short* out = pl ? outB : outA;
        ushort4 oa, ob;
        oa.x = f2bf(a.x); oa.y = f2bf(a.y); oa.z = f2bf(a.z); oa.w = f2bf(a.w);
        ob.x = f2bf(b.x); ob.y = f2bf(b.y); ob.z = f2bf(b.z); ob.w = f2bf(b.w);
        unsigned short* op = out + (size_t)row * DD + lane * 8;
        *(ushort4*)op = oa; *(ushort4*)(op + 4) = ob;
    }
    if (pl != 1) {
        float ax = fmaxf(fmaxf(fmaxf(fabsf(a.x), fabsf(a.y)), fmaxf(fabsf(a.z), fabsf(a.w))),
                         fmaxf(fmaxf(fabsf(b.x), fabsf(b.y)), fmaxf(fabsf(b.z), fabsf(b.w))));
        float s = a.x*a.x + a.y*a.y + a.z*a.z + a.w*a.w
                + b.x*b.x + b.y*b.y + b.z*b.z + b.w*b.w;
        #pragma unroll
        for (int off = 32; off; off >>= 1) {
            ax = fmaxf(ax, __shfl_xor(ax, off, 64));
            if (pl == 0) s += __shfl_xor(s, off, 64);
        }
        ax = fmaxf(ax, 1e-30f);
        float inv = 127.0f / ax;
        int q[8];
        q[0] = __float2int_rn(a.x*inv); q[1] = __float2int_rn(a.y*inv);
        q[2] = __float2int_rn(a.z*inv); q[3] = __float2int_rn(a.w*inv);
        q[4] = __float2int_rn(b.x*inv); q[5] = __float2int_rn(b.y*inv);
        q[6] = __float2int_rn(b.z*inv); q[7] = __float2int_rn(b.w*inv);
        unsigned w0 = (q[0]&255) | ((q[1]&255)<<8) | ((q[2]&255)<<16) | ((unsigned)(q[3]&255)<<24);
        unsigned w1 = (q[4]&255) | ((q[5]&255)<<8) | ((q[6]&255)<<16) | ((unsigned)(q[7]&255)<<24);
        signed char* o8 = (pl == 0 ? outA8 : outV8) + (size_t)row * DD + lane * 8;
        *(uint2*)o8 = make_uint2(w0, w1);
        if (lane == 0) {
            if (pl == 0) { mnorm[row] = s; msc[row] = ax * (1.0f/127.0f); }
            else         { qsc[row] = ax * (1.0f/127.0f); }
        }
    }
}

// ======== Round-13: int8 128x256 kNN GEMM, 2 blocks/CU co-resident ========
// r3 lesson: LDS 129KB -> 1 block/CU -> the epilogue VALU (130K cyc/CU, 2x
// MFMA) had nothing to overlap with. This round: wave-tile 64x64 (acc=64
// VGPR), A-fragments loaded DIRECTLY global->reg (r3 proved the i8 fragment
// k-map: lane quad holds bytes quad*16..+15 -> per-lane dwordx4), B ring-2
// in LDS (32KB) union S (34KB) -> ~35KB LDS, ~116 VGPR -> 2 blocks/CU.
// Per tile t: [af(t) 4x global dwordx4][STG_B(t+1) 2 DMA][vmcnt(2): drains
// B(t)+af(t), leaves B(t+1)][barrier][RD_B 4x ds_read_b128][lgkm(0)]
// [16 MFMA][barrier].  B path byte-identical to r3 (swizzle verified).
__global__ __launch_bounds__(512, 4) void gemm_knn_kernel(
        const signed char* __restrict__ Q8,   // [4096][512] i8
        const signed char* __restrict__ M8,   // [NMEM][512] i8
        const float* __restrict__ mnorm, const float* __restrict__ msc,
        const float* __restrict__ qsc,
        unsigned* __restrict__ cand_part) {   // [4096][ENT] packed keys
    __shared__ __align__(16) union {
        struct { signed char B[2][256][64]; } g;   // 32 KB (ring-2)
        unsigned S[64 * 133];                      // 34 KB (epilogue overlay)
    } sh;
    __shared__ float qs[128];
    const int tid  = threadIdx.x;
    const int lane = tid & 63;
    const int wave = tid >> 6;
    const int quad = lane >> 4, c16 = lane & 15;
    const int wm = wave >> 2, wn = wave & 3;          // 2 x 4 wave grid
    const int m0 = blockIdx.y * 128, n0 = blockIdx.x * 256;
    // B staging identity: 512 threads cover 128 rows x 4 chunks of 16B
    const int srow   = tid >> 2;                      // [0,128)
    const int schunk = (tid & 3) ^ ((tid >> 3) & 3);  // pre-swizzled source chunk
    const signed char* bg = M8 + (size_t)(n0 + srow) * DD + schunk * 16;
    const int cq = (quad ^ ((c16 >> 1) & 3)) * 16;    // reader chunk (swizzled), bytes
    // A fragment base: row = m0 + wm*64 + mt*16 + c16, k-bytes quad*16
    const signed char* agb = Q8 + (size_t)(m0 + wm * 64 + c16) * DD + quad * 16;

    i32x4 acc[4][4] = {};
    i32x4 af[4], bf[4];

    if (tid < 128) qs[tid] = qsc[m0 + tid];

#define STG_B(tt) do {                                                          \
    const int s_ = (tt) & 1;                                                    \
    async_copy16(bg + (size_t)(tt)*64,            &sh.g.B[s_][srow][(tid & 3) * 16]);      \
    async_copy16(bg + (size_t)(tt)*64 + 128*DD,   &sh.g.B[s_][128 + srow][(tid & 3) * 16]);\
} while (0)
#define RD_B(tt) do {                                                           \
    const int s_ = (tt) & 1;                                                    \
    _Pragma("unroll")                                                           \
    for (int nt = 0; nt < 4; ++nt)                                              \
        bf[nt] = *(const i32x4*)&sh.g.B[s_][wn*64 + nt*16 + c16][cq];           \
} while (0)
#define MM() do {                                                               \
    _Pragma("unroll")                                                           \
    for (int mt = 0; mt < 4; ++mt)                                              \
        _Pragma("unroll")                                                       \
        for (int nt = 0; nt < 4; ++nt)                                          \
            acc[mt][nt] = __builtin_amdgcn_mfma_i32_16x16x64_i8(                \
                af[mt], bf[nt], acc[mt][nt], 0, 0, 0);                          \
} while (0)

    // prologue: stage tiles 0 and 1 (ring-2 full)
    STG_B(0); STG_B(1);

    #pragma unroll
    for (int t = 0; t < 8; ++t) {
        // A fragments for tile t, direct from global (compiler-tracked loads)
        #pragma unroll
        for (int mt = 0; mt < 4; ++mt)
            af[mt] = *(const i32x4*)(agb + (size_t)mt * 16 * DD + t * 64);
        if (t >= 1 && t < 7) STG_B(t + 1);
        // ledger: entering [B(t):2] (+B(1):2 at t=0); +af:4; +B(t+1):2.
        // vmcnt(2) drains B(t)+af, leaves B(t+1). t=0/7: drain all.
        if (t == 0 || t == 7) asm volatile("s_waitcnt vmcnt(0)" ::: "memory");
        else                  asm volatile("s_waitcnt vmcnt(2)" ::: "memory");
        __builtin_amdgcn_sched_barrier(0);
        __builtin_amdgcn_s_barrier();           // cross-wave B(t) visibility
        RD_B(t);
        asm volatile("s_waitcnt lgkmcnt(0)" ::: "memory");
        __builtin_amdgcn_sched_barrier(0);
        __builtin_amdgcn_s_setprio(1);
        MM();
        __builtin_amdgcn_s_setprio(0);
        __builtin_amdgcn_sched_barrier(0);
        __builtin_amdgcn_s_barrier();           // orders reads before next STG
    }
#undef STG_B
#undef RD_B
#undef MM

    // ---- selection epilogue: 4 passes of 64 cols; exact top-4 per 64-col group ----
    // S overlay [64 col-slots][133]: write 128 rows x 64 cols per pass; scan:
    // thread (rrow=tid>>2, rq=tid&3) scans 16 slots -> sorted-4; two bitonic
    // shfl-merge levels (rq^1 then rq^2) -> exact top-4 of 64 (tournament).
    // cand layout/decode identical to r2/r3 (16 keys/block, group p at p*4).
    float mn[4], ms2[4];
    #pragma unroll
    for (int nt = 0; nt < 4; ++nt) {
        int col = n0 + wn*64 + nt*16 + c16;
        mn[nt]  = mnorm[col];
        ms2[nt] = -2.0f * msc[col];
    }
    float qsr[4][4];
    #pragma unroll
    for (int mt = 0; mt < 4; ++mt)
        #pragma unroll
        for (int r = 0; r < 4; ++r)
            qsr[mt][r] = qs[wm*64 + mt*16 + quad*4 + r];
    const int rrow = tid >> 2, rq = tid & 3;
    __syncthreads();   // main-loop LDS reads done; DMA drained at t=7
    #pragma unroll
    for (int p = 0; p < 4; ++p) {
        if (wn == p) {
            #pragma unroll
            for (int mt = 0; mt < 4; ++mt)
                #pragma unroll
                for (int nt = 0; nt < 4; ++nt) {
                    uint4 w;
                    #pragma unroll
                    for (int r = 0; r < 4; ++r) {
                        float coef = ms2[nt] * qsr[mt][r];
                        float s = fmaxf(fmaf(coef, (float)acc[mt][nt][r], mn[nt]), 0.f);
                        (&w.x)[r] = (__float_as_uint(s) & 0xFFFFFF80u)
                                  | (unsigned)((p & 1) * 64 + nt * 16 + c16);
                    }
                    *(uint4*)&sh.S[(nt*16 + c16) * 133 + wm*64 + mt*16 + quad*4] = w;
                }
        }
        __syncthreads();
        unsigned s0 = 0xFFFFFFFFu, s1 = 0xFFFFFFFFu, s2 = 0xFFFFFFFFu, s3 = 0xFFFFFFFFu;
        #pragma unroll
        for (int m = 0; m < 16; ++m) {
            unsigned nv = sh.S[(rq*16 + m) * 133 + rrow];
            unsigned lo;
            lo = min(s0, nv); nv = max(s0, nv); s0 = lo;
            lo = min(s1, nv); nv = max(s1, nv); s1 = lo;
            lo = min(s2, nv); nv = max(s2, nv); s2 = lo;
            lo = min(s3, nv); nv = max(s3, nv); s3 = lo;
        }
        // merge level 1 (rq^1): bitonic min-merge + sort (exact top-4 of 32)
        unsigned p0 = (unsigned)__shfl_xor((int)s0, 1, 64);
        unsigned p1 = (unsigned)__shfl_xor((int)s1, 1, 64);
        unsigned p2 = (unsigned)__shfl_xor((int)s2, 1, 64);
        unsigned p3 = (unsigned)__shfl_xor((int)s3, 1, 64);
        unsigned b0 = min(s0, p3), b1 = min(s1, p2), b2 = min(s2, p1), b3 = min(s3, p0);
        unsigned t0 = min(b0, b2), t2 = max(b0, b2), t1 = min(b1, b3), t3 = max(b1, b3);
        s0 = min(t0, t1); s1 = max(t0, t1); s2 = min(t2, t3); s3 = max(t2, t3);
        // merge level 2 (rq^2): exact top-4 of 64 (order irrelevant)
        p0 = (unsigned)__shfl_xor((int)s0, 2, 64);
        p1 = (unsigned)__shfl_xor((int)s1, 2, 64);
        p2 = (unsigned)__shfl_xor((int)s2, 2, 64);
        p3 = (unsigned)__shfl_xor((int)s3, 2, 64);
        b0 = min(s0, p3); b1 = min(s1, p2); b2 = min(s2, p1); b3 = min(s3, p0);
        if (rq == p) {
            *(uint4*)(cand_part + (size_t)(m0 + rrow) * ENT + blockIdx.x * 16 + p * 4) =
                make_uint4(b0, b1, b2, b3);
        }
        __syncthreads();
    }
}

// ---------------- fused select: scan 2048 keys -> exact top-16 -> fp32 rescore -> top-10 ----
// One block (4 waves) per row. Each wave extracts top-16 (round-7 lesson:
// per-wave cap must be >= global survivor count); wave 0 merges 64 -> exact
// top-16 of cand_part; exact fp32 rescore -> top-10.
__global__ __launch_bounds__(256) void knn_select_kernel(
        const unsigned* __restrict__ cand_part,  // [4096][ENT] packed keys
        const float* __restrict__ Q, const float* __restrict__ Mm,
        const float* __restrict__ mnorm,
        int* __restrict__ knn_idx) {
    const int row = blockIdx.x;
    const int wave = threadIdx.x >> 6, lane = threadIdx.x & 63;
    __shared__ unsigned sk[64];
    __shared__ int      sc[64];
    __shared__ int      ids[NCF];
    __shared__ float    d2s[NCF];

    // phase A: per-lane top-6 over this wave's 512 keys (8/lane, uint4 loads)
    unsigned ks[LK]; int ti[LK];
    #pragma unroll
    for (int q = 0; q < LK; ++q) { ks[q] = 0xFFFFFFFFu; ti[q] = IMAX; }
    const uint4* p4 = (const uint4*)(cand_part + (size_t)row * ENT) + wave * 128;
    #pragma unroll
    for (int i = 0; i < 2; ++i) {
        uint4 v = p4[lane + 64 * i];
        #pragma unroll
        for (int e = 0; e < 4; ++e) {
            unsigned k = (&v.x)[e];
            int pos = wave * 512 + (lane + 64 * i) * 4 + e;
            int gcol = (pos >> 3) * 128 + (int)(k & 127u);
            bool cm[LK];
            #pragma unroll
            for (int q = 0; q < LK; ++q) cm[q] = k < ks[q];
            #pragma unroll
            for (int q = LK - 1; q > 0; --q) {
                unsigned tns = cm[q] ? k : ks[q];  int tni = cm[q] ? gcol : ti[q];
                ks[q] = cm[q-1] ? ks[q-1] : tns;
                ti[q] = cm[q-1] ? ti[q-1] : tni;
            }
            ks[0] = cm[0] ? k : ks[0];
            ti[0] = cm[0] ? gcol : ti[0];
        }
    }
    // phase B: per-wave top-16 via argmin extraction
    #pragma unroll
    for (int r = 0; r < NCF; ++r) {
        unsigned mk = ks[0]; int mi = ti[0];
        #pragma unroll
        for (int off = 1; off < 64; off <<= 1) {
            unsigned ok = (unsigned)__shfl_xor((int)mk, off, 64);
            int      oi = __shfl_xor(mi, off, 64);
            bool t = (ok < mk) || (ok == mk && oi < mi);
            mk = t ? ok : mk; mi = t ? oi : mi;
        }
        bool win = (ks[0] == mk) && (ti[0] == mi);
        #pragma unroll
        for (int q = 0; q < LK - 1; ++q) {
            ks[q] = win ? ks[q+1] : ks[q];
            ti[q] = win ? ti[q+1] : ti[q];
        }
        ks[LK-1] = win ? 0xFFFFFFFFu : ks[LK-1];
        ti[LK-1] = win ? IMAX : ti[LK-1];
        if (lane == r) { sk[wave * NCF + r] = mk; sc[wave * NCF + r] = mi; }
    }
    __syncthreads();
    // phase C: wave 0 merges 64 -> exact top-16
    if (wave == 0) {
        unsigned myk = sk[lane];
        int      myc = sc[lane];
        #pragma unroll
        for (int r = 0; r < NCF; ++r) {
            unsigned mk = myk; int mi = myc;
            #pragma unroll
            for (int off = 1; off < 64; off <<= 1) {
                unsigned ok = (unsigned)__shfl_xor((int)mk, off, 64);
                int      oi = __shfl_xor(mi, off, 64);
                bool t = (ok < mk) || (ok == mk && oi < mi);
                mk = t ? ok : mk; mi = t ? oi : mi;
            }
            bool win = (myk == mk) && (myc == mi);
            myk = win ? 0xFFFFFFFFu : myk;
            myc = win ? IMAX : myc;
            if (lane == r) ids[r] = mi;
        }
    }
    __syncthreads();
    // phase D: exact fp32 rescore of 16 candidates
    float4 q0 = *(const float4*)(Q + (size_t)row * DD + lane * 8);
    float4 q1 = *(const float4*)(Q + (size_t)row * DD + lane * 8 + 4);
    for (int c = wave; c < NCF; c += 4) {
        int j = ids[c];
        const float* mr = Mm + (size_t)j * DD;
        float4 m0 = *(const float4*)(mr + lane * 8);
        float4 m1 = *(const float4*)(mr + lane * 8 + 4);
        float dot = q0.x*m0.x + q0.y*m0.y + q0.z*m0.z + q0.w*m0.w
                  + q1.x*m1.x + q1.y*m1.y + q1.z*m1.z + q1.w*m1.w;
        #pragma unroll
        for (int off = 32; off; off >>= 1) dot += __shfl_xor(dot, off, 64);
        if (lane == 0) d2s[c] = fmaf(-2.f, dot, mnorm[j]);
    }
    __syncthreads();
    // phase E: top-10 (exact lexicographic)
    if (threadIdx.x == 0) {
        float ts[TOPN]; int tj[TOPN];
        #pragma unroll
        for (int p = 0; p < TOPN; ++p) { ts[p] = FINF; tj[p] = IMAX; }
        for (int c = 0; c < NCF; ++c) topk_insert<TOPN>(ts, tj, d2s[c], ids[c]);
        #pragma unroll
        for (int p = 0; p < TOPN; ++p) knn_idx[row * TOPN + p] = tj[p];
    }
}

// ---------------- unified bf16 MFMA GEMM (m97 structure, swizzled LDS) ----------------
template<int ACT, int OUT_BF16>
__global__ __launch_bounds__(256) void gemm_bf16_nt(
        const unsigned short* __restrict__ A,
        const unsigned short* __restrict__ B,
        const float* __restrict__ bias,
        void* __restrict__ Cout, int ldc) {
    __shared__ __align__(16) unsigned short As[128 * 64];
    __shared__ __align__(16) unsigned short Bs[128 * 64];
    const int tid  = threadIdx.x;
    const int wave = tid >> 6, lane = tid & 63;
    const int quad = lane >> 4, c16 = lane & 15;
    const int m0 = blockIdx.y * 128, n0 = blockIdx.x * 128;
    const int wm0 = (wave >> 1) * 64, wn0 = (wave & 1) * 64;
    const int srow = wave * 32 + (lane >> 3);
    const int schunk = (lane & 7) ^ ((lane >> 3) & 7);
    const int xsw = c16 & 7;

    f32x4 acc[4][4] = {};

    for (int kt = 0; kt < DD; kt += 64) {
        __syncthreads();
        #pragma unroll
        for (int i = 0; i < 4; ++i) {
            const unsigned short* ga = A + (size_t)(m0 + srow + i * 8) * DD + kt + schunk * 8;
            async_copy16(ga, &As[(wave * 32 + i * 8) * 64]);
            const unsigned short* gb = B + (size_t)(n0 + srow + i * 8) * DD + kt + schunk * 8;
            async_copy16(gb, &Bs[(wave * 32 + i * 8) * 64]);
        }
        __syncthreads();
        #pragma unroll
        for (int ks = 0; ks < 64; ks += 32) {
            const int coff = (((ks >> 3) + quad) ^ xsw) << 3;
            bf16x8 af[4], bff[4];
            #pragma unroll
            for (int mt = 0; mt < 4; ++mt)
                af[mt] = *(const bf16x8*)&As[(wm0 + mt * 16 + c16) * 64 + coff];
            #pragma unroll
            for (int nt = 0; nt < 4; ++nt)
                bff[nt] = *(const bf16x8*)&Bs[(wn0 + nt * 16 + c16) * 64 + coff];
            #pragma unroll
            for (int mt = 0; mt < 4; ++mt)
                #pragma unroll
                for (int nt = 0; nt < 4; ++nt)
                    acc[mt][nt] = __builtin_amdgcn_mfma_f32_16x16x32_bf16(
                        af[mt], bff[nt], acc[mt][nt], 0, 0, 0);
        }
    }
    #pragma unroll
    for (int nt = 0; nt < 4; ++nt) {
        int ncol = n0 + wn0 + nt * 16 + c16;
        float bv = bias[ncol];
        #pragma unroll
        for (int mt = 0; mt < 4; ++mt) {
            size_t rbase = (size_t)(m0 + wm0 + mt * 16 + quad * 4) * ldc + ncol;
            #pragma unroll
            for (int r = 0; r < 4; ++r) {
                float v = acc[mt][nt][r] + bv;
                if (ACT == 1) v = v >= 0.f ? v : 0.01f * v;
                if (OUT_BF16) ((unsigned short*)Cout)[rbase + (size_t)r * ldc] = f2bf(v);
                else          ((float*)Cout)[rbase + (size_t)r * ldc] = v;
            }
        }
    }
}

// ---------------- K/V/q projections in ONE dispatch (compacted y-grid) ----------------
// y in [0,256) -> K; [256,512) -> V; [512,544) -> q.  No dead blocks.
struct G3 {
    const unsigned short* A[3];
    const unsigned short* B[3];
    const float* bias[3];
    void* C[3];
    int obf[3];
};
__global__ __launch_bounds__(256) void gemm3_kernel(G3 g) {
    const int yy = blockIdx.y;
    const int z = (yy >= 512) ? 2 : (yy >= 256 ? 1 : 0);
    const int my = yy - z * 256;
    __shared__ __align__(16) unsigned short As[128 * 64];
    __shared__ __align__(16) unsigned short Bs[128 * 64];
    const unsigned short* A = g.A[z];
    const unsigned short* B = g.B[z];
    const int tid  = threadIdx.x;
    const int wave = tid >> 6, lane = tid & 63;
    const int quad = lane >> 4, c16 = lane & 15;
    const int m0 = my * 128, n0 = blockIdx.x * 128;
    const int wm0 = (wave >> 1) * 64, wn0 = (wave & 1) * 64;
    const int srow = wave * 32 + (lane >> 3);
    const int schunk = (lane & 7) ^ ((lane >> 3) & 7);
    const int xsw = c16 & 7;

    f32x4 acc[4][4] = {};

    for (int kt = 0; kt < DD; kt += 64) {
        __syncthreads();
        #pragma unroll
        for (int i = 0; i < 4; ++i) {
            const unsigned short* ga = A + (size_t)(m0 + srow + i * 8) * DD + kt + schunk * 8;
            async_copy16(ga, &As[(wave * 32 + i * 8) * 64]);
            const unsigned short* gb = B + (size_t)(n0 + srow + i * 8) * DD + kt + schunk * 8;
            async_copy16(gb, &Bs[(wave * 32 + i * 8) * 64]);
        }
        __syncthreads();
        #pragma unroll
        for (int ks = 0; ks < 64; ks += 32) {
            const int coff = (((ks >> 3) + quad) ^ xsw) << 3;
            bf16x8 af[4], bff[4];
            #pragma unroll
            for (int mt = 0; mt < 4; ++mt)
                af[mt] = *(const bf16x8*)&As[(wm0 + mt * 16 + c16) * 64 + coff];
            #pragma unroll
            for (int nt = 0; nt < 4; ++nt)
                bff[nt] = *(const bf16x8*)&Bs[(wn0 + nt * 16 + c16) * 64 + coff];
            #pragma unroll
            for (int mt = 0; mt < 4; ++mt)
                #pragma unroll
                for (int nt = 0; nt < 4; ++nt)
                    acc[mt][nt] = __builtin_amdgcn_mfma_f32_16x16x32_bf16(
                        af[mt], bff[nt], acc[mt][nt], 0, 0, 0);
        }
    }
    const int obf = g.obf[z];
    #pragma unroll
    for (int nt = 0; nt < 4; ++nt) {
        int ncol = n0 + wn0 + nt * 16 + c16;
        float bv = g.bias[z][ncol];
        #pragma unroll
        for (int mt = 0; mt < 4; ++mt) {
            size_t rbase = (size_t)(m0 + wm0 + mt * 16 + quad * 4) * DD + ncol;
            #pragma unroll
            for (int r = 0; r < 4; ++r) {
                float v = acc[mt][nt][r] + bv;
                if (obf) ((unsigned short*)g.C[z])[rbase + (size_t)r * DD] = f2bf(v);
                else     ((float*)g.C[z])[rbase + (size_t)r * DD] = v;
            }
        }
    }
}

// ---------------- attention: one block per query row, one wave per head ----------------
__global__ __launch_bounds__(512) void attn_kernel(
        const float* __restrict__ qh, const unsigned short* __restrict__ Kall,
        const unsigned short* __restrict__ Vall, const int* __restrict__ knn_idx,
        unsigned short* __restrict__ ctx_b) {
    const int b = blockIdx.x;
    const int h = threadIdx.x >> 6;
    const int l = threadIdx.x & 63;
    const int col = (h << 6) + l;
    int idxs[TOPN];
    #pragma unroll
    for (int n = 0; n < TOPN; ++n) idxs[n] = knn_idx[b * TOPN + n];
    const float q = qh[(size_t)b * DD + col];
    float sc[TOPN];
    #pragma unroll
    for (int n = 0; n < TOPN; ++n) {
        float p = q * __uint_as_float((unsigned)Kall[(size_t)idxs[n] * DD + col] << 16);
        #pragma unroll
        for (int off = 32; off; off >>= 1) p += __shfl_xor(p, off, 64);
        sc[n] = p * 0.125f;
    }
    float mx = sc[0];
    #pragma unroll
    for (int n = 1; n < TOPN; ++n) mx = fmaxf(mx, sc[n]);
    float se = 0.f;
    #pragma unroll
    for (int n = 0; n < TOPN; ++n) { sc[n] = expf(sc[n] - mx); se += sc[n]; }
    const float inv = 1.f / se;
    float o = 0.f;
    #pragma unroll
    for (int n = 0; n < TOPN; ++n)
        o = fmaf(sc[n] * inv,
                 __uint_as_float((unsigned)Vall[(size_t)idxs[n] * DD + col] << 16), o);
    ctx_b[(size_t)b * DD + col] = f2bf(o);
}

// ---------------- residual add + layernorm (optional bf16 secondary output) ----------------
template<int EMIT_BF16>
__global__ __launch_bounds__(256) void add_ln_kernel(
        const float* __restrict__ X, const float* __restrict__ Y,
        const float* __restrict__ g, const float* __restrict__ be,
        float* __restrict__ out, unsigned short* __restrict__ out_b) {
    const int row = blockIdx.x;
    const int t = threadIdx.x;
    const size_t base = (size_t)row * DD;
    float v0 = X[base + t]       + Y[base + t];
    float v1 = X[base + 256 + t] + Y[base + 256 + t];
    float s = v0 + v1, sq = v0 * v0 + v1 * v1;
    #pragma unroll
    for (int off = 32; off; off >>= 1) { s += __shfl_xor(s, off, 64); sq += __shfl_xor(sq, off, 64); }
    __shared__ float rs[4], rq[4];
    const int w = t >> 6, l = t & 63;
    if (l == 0) { rs[w] = s; rq[w] = sq; }
    __syncthreads();
    float tot  = rs[0] + rs[1] + rs[2] + rs[3];
    float totq = rq[0] + rq[1] + rq[2] + rq[3];
    float mu = tot * (1.f / DD);
    float var = totq * (1.f / DD) - mu * mu;
    float rstd = rsqrtf(var + 1e-5f);
    float o0 = (v0 - mu) * rstd * g[t]       + be[t];
    float o1 = (v1 - mu) * rstd * g[256 + t] + be[256 + t];
    out[base + t] = o0;
    out[base + 256 + t] = o1;
    if (EMIT_BF16) {
        out_b[base + t] = f2bf(o0);
        out_b[base + 256 + t] = f2bf(o1);
    }
}

// ---------------- launch ----------------
extern "C" void kernel_launch(void* const* d_in, const int* in_sizes, int n_in,
                              void* d_out, int out_size, void* d_ws, size_t ws_size,
                              hipStream_t stream) {
    const float* visit = (const float*)d_in[0];
    const float* Epat  = (const float*)d_in[1];
    const float* Emed  = (const float*)d_in[2];
    const float* Wq = (const float*)d_in[3];
    const float* Wk = (const float*)d_in[4];
    const float* Wv = (const float*)d_in[5];
    const float* bq = (const float*)d_in[6];
    const float* bk = (const float*)d_in[7];
    const float* bv = (const float*)d_in[8];
    const float* Wo = (const float*)d_in[9];
    const float* bo = (const float*)d_in[10];
    const float* W1 = (const float*)d_in[11];
    const float* b1 = (const float*)d_in[12];
    const float* W2 = (const float*)d_in[13];
    const float* b2 = (const float*)d_in[14];
    const float* ln1g = (const float*)d_in[15];
    const float* ln1b = (const float*)d_in[16];
    const float* ln2g = (const float*)d_in[17];
    const float* ln2b = (const float*)d_in[18];
    float* out = (float*)d_out;

    // ---- workspace layout, ~174 MB peak ----
    char* base = (char*)d_ws;
    const size_t MB = 1u << 20;
    float* mnorm   = (float*)(base);                    // 128 KB
    float* msc     = (float*)(base + 256*1024);         // 128 KB (Epat row scales)
    float* qsc     = (float*)(base + 512*1024);         // 16 KB  (visit row scales)
    int*   knn_idx = (int*)  (base + 2*MB);             // 160 KB
    float* qh      = (float*)(base + 3*MB);             // 8 MB
    float* attn_o  = qh;                                // alias: qh dead after attn
    float* x1      = (float*)(base + 11*MB);            // 8 MB
    float* ff      = (float*)(base + 19*MB);            // 8 MB
    unsigned short* Qb    = (unsigned short*)(base + 27*MB);  // 4 MB (visit bf16)
    unsigned short* ctx_b = (unsigned short*)(base + 31*MB);  // 4 MB
    unsigned short* x1_b  = (unsigned short*)(base + 35*MB);  // 4 MB
    unsigned short* h1_b  = (unsigned short*)(base + 39*MB);  // 4 MB
    unsigned short* Wq_b  = (unsigned short*)(base + 43*MB);  // 6 x 512 KB
    unsigned short* Wk_b  = Wq_b + 262144;
    unsigned short* Wv_b  = Wk_b + 262144;
    unsigned short* Wo_b  = Wv_b + 262144;
    unsigned short* W1_b  = Wo_b + 262144;
    unsigned short* W2_b  = W1_b + 262144;
    unsigned short* Mb     = (unsigned short*)(base + 46*MB); // 32 MB (Epat bf16)
    unsigned short* Emed_b = (unsigned short*)(base + 78*MB); // 32 MB
    // K|V region (64 MB bf16); cand_part (32 MB) aliases Kall during kNN phase;
    // M8 (16 MB) + Q8 (2 MB) alias Vall (dead until gemm3).
    unsigned short* Kall = (unsigned short*)(base + 110*MB);  // 32 MB
    unsigned short* Vall = Kall + (size_t)NMEM * DD;          // 32 MB
    unsigned* cand_part = (unsigned*)Kall;                    // alias (kNN only)
    signed char* M8 = (signed char*)(base + 142*MB);          // alias Vall[0:16MB)
    signed char* Q8 = (signed char*)(base + 158*MB);          // alias Vall[16:18MB)

    // ---- casts + norms + int8 quant (2 dispatches total) ----
    cast_norm2_kernel<<<dim3(NMEM / 4, 3), 256, 0, stream>>>(
        Epat, Mb, Emed, Emed_b, visit, M8, Q8, mnorm, msc, qsc);
    CastDesc cd;
    cd.in[0] = visit; cd.out[0] = Qb;
    cd.in[1] = Wq; cd.in[2] = Wk; cd.in[3] = Wv; cd.in[4] = Wo; cd.in[5] = W1; cd.in[6] = W2;
    cd.out[1] = Wq_b; cd.out[2] = Wk_b; cd.out[3] = Wv_b; cd.out[4] = Wo_b; cd.out[5] = W1_b; cd.out[6] = W2_b;
    cd.start[0] = 0; cd.start[1] = 2048;
    for (int s = 2; s <= 7; ++s) cd.start[s] = cd.start[s-1] + 256;
    cast_multi_kernel<<<cd.start[7], 256, 0, stream>>>(cd);

    // ---- kNN: int8 MFMA scores + selection -> fused merge+rescore ----
    gemm_knn_kernel<<<dim3(NBX, BQ / 128), 512, 0, stream>>>(Q8, M8, mnorm, msc, qsc, cand_part);
    knn_select_kernel<<<BQ, 256, 0, stream>>>(cand_part, visit, Epat, mnorm, knn_idx);

    // ---- K/V/q projections in one compacted dispatch (Kall write overwrites cand_part;
    //      Vall write overwrites M8/Q8 — both dead by then)
    G3 g3;
    g3.A[0] = Mb;     g3.B[0] = Wk_b; g3.bias[0] = bk; g3.C[0] = Kall; g3.obf[0] = 1;
    g3.A[1] = Emed_b; g3.B[1] = Wv_b; g3.bias[1] = bv; g3.C[1] = Vall; g3.obf[1] = 1;
    g3.A[2] = Qb;     g3.B[2] = Wq_b; g3.bias[2] = bq; g3.C[2] = qh;   g3.obf[2] = 0;
    gemm3_kernel<<<dim3(4, 544), 256, 0, stream>>>(g3);

    attn_kernel<<<BQ, 512, 0, stream>>>(qh, Kall, Vall, knn_idx, ctx_b);

    gemm_bf16_nt<0,0><<<dim3(4, BQ / 128), 256, 0, stream>>>(ctx_b, Wo_b, bo, attn_o, DD);
    add_ln_kernel<1><<<BQ, 256, 0, stream>>>(visit, attn_o, ln1g, ln1b, x1, x1_b);
    gemm_bf16_nt<1,1><<<dim3(4, BQ / 128), 256, 0, stream>>>(x1_b, W1_b, b1, h1_b, DD);
    gemm_bf16_nt<0,0><<<dim3(4, BQ / 128), 256, 0, stream>>>(h1_b, W2_b, b2, ff,   DD);
    add_ln_kernel<0><<<BQ, 256, 0, stream>>>(x1, ff, ln2g, ln2b, out, nullptr);
}

// Round 5
// 536.066 us; speedup vs baseline: 1.4311x; 1.4311x over previous
//
#include <hip/hip_runtime.h>
#include <math.h>

#define BQ 4096
#define NMEM 32768
#define DD 512
#define TOPN 10
#define NBX 128                  /* 256-col blocks over NMEM */
#define ENT 2048                 /* candidate entries per row = NBX*16 */
#define NCF 16                   /* final candidates per row */
#define LK 6                     /* per-lane top-K in knn_select scan */
#define FINF 3.402823466e+38f
#define IMAX 0x7fffffff

typedef __attribute__((ext_vector_type(8))) short    bf16x8;
typedef __attribute__((ext_vector_type(4))) float    f32x4;
typedef __attribute__((ext_vector_type(4))) int      i32x4;

// ---------------- helpers ----------------
__device__ __forceinline__ unsigned short f2bf(float x) {
    unsigned int u = __float_as_uint(x);
    u += 0x7fffu + ((u >> 16) & 1u);          // round-to-nearest-even
    return (unsigned short)(u >> 16);
}
__device__ __forceinline__ void async_copy16(const void* gp, void* lp) {
    __builtin_amdgcn_global_load_lds(
        (const __attribute__((address_space(1))) void*)gp,
        (__attribute__((address_space(3))) void*)lp, 16, 0, 0);
}
__device__ __forceinline__ bool lt_si(float s, int j, float s2, int j2) {
    return (s < s2) || (s == s2 && j < j2);   // matches top_k tie-break
}
template<int KN>
__device__ __forceinline__ void topk_insert(float (&ts)[KN], int (&ti)[KN], float s, int j) {
    if (!lt_si(s, j, ts[KN-1], ti[KN-1])) return;
    #pragma unroll
    for (int p = KN-1; p > 0; --p) {
        if (lt_si(s, j, ts[p-1], ti[p-1])) { ts[p] = ts[p-1]; ti[p] = ti[p-1]; }
        else { ts[p] = s; ti[p] = j; return; }
    }
    ts[0] = s; ti[0] = j;
}

// ---------------- segmented cast: visit + 6 weight matrices in ONE dispatch ----------------
struct CastDesc {
    const float* in[7];
    unsigned short* out[7];
    int start[8];   // cumulative block starts, start[7] = total
};
__global__ __launch_bounds__(256) void cast_multi_kernel(CastDesc d) {
    int blk = blockIdx.x;
    int seg = 0;
    #pragma unroll
    for (int s = 0; s < 6; ++s) seg += (blk >= d.start[s + 1]) ? 1 : 0;
    int local = blk - d.start[seg];
    int i = (local * 256 + threadIdx.x) * 4;
    float4 v = *(const float4*)(d.in[seg] + i);
    ushort4 o;
    o.x = f2bf(v.x); o.y = f2bf(v.y); o.z = f2bf(v.z); o.w = f2bf(v.w);
    *(ushort4*)(d.out[seg] + i) = o;
}

// ---------------- fused cast planes over Epat/Emed/visit ----------------
// y==0: Epat -> bf16 + int8(+scale) + ||row||^2 ; y==1: Emed -> bf16 ;
// y==2 (x<1024): visit -> int8(+scale).
// int8 quant: per-row symmetric absmax/127 (d2-error std ~0.5 vs rank
// spacing ~0.45/rank; survivors rescored exact fp32 -> selection-safe).
__global__ __launch_bounds__(256) void cast_norm2_kernel(
        const float* __restrict__ inA, unsigned short* __restrict__ outA,
        const float* __restrict__ inB, unsigned short* __restrict__ outB,
        const float* __restrict__ inV,
        signed char* __restrict__ outA8, signed char* __restrict__ outV8,
        float* __restrict__ mnorm, float* __restrict__ msc,
        float* __restrict__ qsc) {
    const int pl = blockIdx.y;
    if (pl == 2 && blockIdx.x >= BQ / 4) return;
    const float* in = (pl == 0) ? inA : (pl == 1 ? inB : inV);
    int row = blockIdx.x * 4 + (threadIdx.x >> 6);
    int lane = threadIdx.x & 63;
    const float* r = in + (size_t)row * DD + lane * 8;
    float4 a = *(const float4*)r;
    float4 b = *(const float4*)(r + 4);
    if (pl < 2) {
        unsigned short* out = pl ? outB : outA;
        ushort4 oa, ob;
        oa.x = f2bf(a.x); oa.y = f2bf(a.y); oa.z = f2bf(a.z); oa.w = f2bf(a.w);
        ob.x = f2bf(b.x); ob.y = f2bf(b.y); ob.z = f2bf(b.z); ob.w = f2bf(b.w);
        unsigned short* op = out + (size_t)row * DD + lane * 8;
        *(ushort4*)op = oa; *(ushort4*)(op + 4) = ob;
    }
    if (pl != 1) {
        float ax = fmaxf(fmaxf(fmaxf(fabsf(a.x), fabsf(a.y)), fmaxf(fabsf(a.z), fabsf(a.w))),
                         fmaxf(fmaxf(fabsf(b.x), fabsf(b.y)), fmaxf(fabsf(b.z), fabsf(b.w))));
        float s = a.x*a.x + a.y*a.y + a.z*a.z + a.w*a.w
                + b.x*b.x + b.y*b.y + b.z*b.z + b.w*b.w;
        #pragma unroll
        for (int off = 32; off; off >>= 1) {
            ax = fmaxf(ax, __shfl_xor(ax, off, 64));
            if (pl == 0) s += __shfl_xor(s, off, 64);
        }
        ax = fmaxf(ax, 1e-30f);
        float inv = 127.0f / ax;
        int q[8];
        q[0] = __float2int_rn(a.x*inv); q[1] = __float2int_rn(a.y*inv);
        q[2] = __float2int_rn(a.z*inv); q[3] = __float2int_rn(a.w*inv);
        q[4] = __float2int_rn(b.x*inv); q[5] = __float2int_rn(b.y*inv);
        q[6] = __float2int_rn(b.z*inv); q[7] = __float2int_rn(b.w*inv);
        unsigned w0 = (q[0]&255) | ((q[1]&255)<<8) | ((q[2]&255)<<16) | ((unsigned)(q[3]&255)<<24);
        unsigned w1 = (q[4]&255) | ((q[5]&255)<<8) | ((q[6]&255)<<16) | ((unsigned)(q[7]&255)<<24);
        signed char* o8 = (pl == 0 ? outA8 : outV8) + (size_t)row * DD + lane * 8;
        *(uint2*)o8 = make_uint2(w0, w1);
        if (lane == 0) {
            if (pl == 0) { mnorm[row] = s; msc[row] = ax * (1.0f/127.0f); }
            else         { qsc[row] = ax * (1.0f/127.0f); }
        }
    }
}

// ======== Round-14: int8 128x256 kNN GEMM, 2 blocks/CU, LDS-staged A+B ========
// r4 post-mortem: occupancy fix worked (44%) but A-direct-reg + qsr array
// pushed unified regs past the 128 cap -> 280 MB scratch spill in the K-loop.
// This round keeps r4's footprint (128x256 block, wave-tile 64x64, acc=64
// AGPR) but stages BOTH A and B through LDS ring-2 (r3's proven datapath,
// same swizzle): A[2][128][64] 16KB + B[2][256][64] 32KB union S 34KB ->
// 48KB LDS. VGPR ~55 + 64 AGPR ~= 119 unified <= 128 -> no spill.
// One barrier per tile: RD(t) 8x ds_read_b128 | STG(t+1) 3x DMA | lgkm(0) |
// 16 MFMA | vmcnt(0) (lands under MFMA) | s_barrier.
// Ledger: only tile t+1's 3 DMAs in flight at vmcnt(0); W-A-R on slot
// (t+1)&1 safe (its tile t-1 readers drained by lgkm(0) before barrier(t-1),
// which precedes this tile's STG).
__global__ __launch_bounds__(512, 4) void gemm_knn_kernel(
        const signed char* __restrict__ Q8,   // [4096][512] i8
        const signed char* __restrict__ M8,   // [NMEM][512] i8
        const float* __restrict__ mnorm, const float* __restrict__ msc,
        const float* __restrict__ qsc,
        unsigned* __restrict__ cand_part) {   // [4096][ENT] packed keys
    __shared__ __align__(16) union {
        struct { signed char A[2][128][64]; signed char B[2][256][64]; } g; // 48 KB
        unsigned S[64 * 133];                                               // 34 KB
    } sh;
    __shared__ float qs[128];
    const int tid  = threadIdx.x;
    const int lane = tid & 63;
    const int wave = tid >> 6;
    const int quad = lane >> 4, c16 = lane & 15;
    const int wm = wave >> 2, wn = wave & 3;          // 2 x 4 wave grid
    const int m0 = blockIdx.y * 128, n0 = blockIdx.x * 256;
    // staging identity: 512 threads = 128 rows x 4 chunks of 16B
    const int srow   = tid >> 2;                      // [0,128)
    const int schunk = (tid & 3) ^ ((tid >> 3) & 3);  // pre-swizzled source chunk
    const signed char* ag = Q8 + (size_t)(m0 + srow) * DD + schunk * 16;
    const signed char* bg = M8 + (size_t)(n0 + srow) * DD + schunk * 16;
    const int cq = (quad ^ ((c16 >> 1) & 3)) * 16;    // reader chunk (swizzled), bytes

    i32x4 acc[4][4] = {};
    i32x4 af[4], bf[4];

    if (tid < 128) qs[tid] = qsc[m0 + tid];

#define STG(tt) do {                                                            \
    const int s_ = (tt) & 1;                                                    \
    async_copy16(ag + (size_t)(tt)*64,            &sh.g.A[s_][srow][(tid & 3) * 16]);      \
    async_copy16(bg + (size_t)(tt)*64,            &sh.g.B[s_][srow][(tid & 3) * 16]);      \
    async_copy16(bg + (size_t)(tt)*64 + 128*DD,   &sh.g.B[s_][128 + srow][(tid & 3) * 16]);\
} while (0)
#define RD(tt) do {                                                             \
    const int s_ = (tt) & 1;                                                    \
    _Pragma("unroll")                                                           \
    for (int mt = 0; mt < 4; ++mt)                                              \
        af[mt] = *(const i32x4*)&sh.g.A[s_][wm*64 + mt*16 + c16][cq];           \
    _Pragma("unroll")                                                           \
    for (int nt = 0; nt < 4; ++nt)                                              \
        bf[nt] = *(const i32x4*)&sh.g.B[s_][wn*64 + nt*16 + c16][cq];           \
} while (0)
#define MM() do {                                                               \
    _Pragma("unroll")                                                           \
    for (int mt = 0; mt < 4; ++mt)                                              \
        _Pragma("unroll")                                                       \
        for (int nt = 0; nt < 4; ++nt)                                          \
            acc[mt][nt] = __builtin_amdgcn_mfma_i32_16x16x64_i8(                \
                af[mt], bf[nt], acc[mt][nt], 0, 0, 0);                          \
} while (0)

    // prologue: stage tile 0, drain, barrier
    STG(0);
    asm volatile("s_waitcnt vmcnt(0)" ::: "memory");
    __builtin_amdgcn_s_barrier();
    __builtin_amdgcn_sched_barrier(0);

    #pragma unroll
    for (int t = 0; t < 8; ++t) {
        RD(t);
        if (t < 7) STG(t + 1);
        __builtin_amdgcn_sched_barrier(0);
        asm volatile("s_waitcnt lgkmcnt(0)" ::: "memory");
        __builtin_amdgcn_sched_barrier(0);
        __builtin_amdgcn_s_setprio(1);
        MM();
        __builtin_amdgcn_s_setprio(0);
        __builtin_amdgcn_sched_barrier(0);
        asm volatile("s_waitcnt vmcnt(0)" ::: "memory");   // t+1 landed (under MFMA)
        __builtin_amdgcn_sched_barrier(0);
        __builtin_amdgcn_s_barrier();
    }
#undef STG
#undef RD
#undef MM

    // ---- selection epilogue: 4 passes of 64 cols; exact top-4 per 64-col group ----
    // (r4-verified logic; qs read from LDS at use to keep registers <=128)
    // S overlay [64 col-slots][133]: thread (rrow=tid>>2, rq=tid&3) scans 16
    // slots -> sorted-4; two bitonic shfl-merge levels -> exact top-4 of 64.
    // cand layout/decode identical to r2/r3/r4 (16 keys/block, group p at p*4).
    float mn[4], ms2[4];
    #pragma unroll
    for (int nt = 0; nt < 4; ++nt) {
        int col = n0 + wn*64 + nt*16 + c16;
        mn[nt]  = mnorm[col];
        ms2[nt] = -2.0f * msc[col];
    }
    const int rrow = tid >> 2, rq = tid & 3;
    __syncthreads();   // main-loop LDS reads done; DMA drained at t=7
    #pragma unroll
    for (int p = 0; p < 4; ++p) {
        if (wn == p) {
            #pragma unroll
            for (int mt = 0; mt < 4; ++mt)
                #pragma unroll
                for (int nt = 0; nt < 4; ++nt) {
                    uint4 w;
                    #pragma unroll
                    for (int r = 0; r < 4; ++r) {
                        float coef = ms2[nt] * qs[wm*64 + mt*16 + quad*4 + r];
                        float s = fmaxf(fmaf(coef, (float)acc[mt][nt][r], mn[nt]), 0.f);
                        (&w.x)[r] = (__float_as_uint(s) & 0xFFFFFF80u)
                                  | (unsigned)((p & 1) * 64 + nt * 16 + c16);
                    }
                    *(uint4*)&sh.S[(nt*16 + c16) * 133 + wm*64 + mt*16 + quad*4] = w;
                }
        }
        __syncthreads();
        unsigned s0 = 0xFFFFFFFFu, s1 = 0xFFFFFFFFu, s2 = 0xFFFFFFFFu, s3 = 0xFFFFFFFFu;
        #pragma unroll
        for (int m = 0; m < 16; ++m) {
            unsigned nv = sh.S[(rq*16 + m) * 133 + rrow];
            unsigned lo;
            lo = min(s0, nv); nv = max(s0, nv); s0 = lo;
            lo = min(s1, nv); nv = max(s1, nv); s1 = lo;
            lo = min(s2, nv); nv = max(s2, nv); s2 = lo;
            lo = min(s3, nv); nv = max(s3, nv); s3 = lo;
        }
        // merge level 1 (rq^1): bitonic min-merge + sort (exact top-4 of 32)
        unsigned p0 = (unsigned)__shfl_xor((int)s0, 1, 64);
        unsigned p1 = (unsigned)__shfl_xor((int)s1, 1, 64);
        unsigned p2 = (unsigned)__shfl_xor((int)s2, 1, 64);
        unsigned p3 = (unsigned)__shfl_xor((int)s3, 1, 64);
        unsigned b0 = min(s0, p3), b1 = min(s1, p2), b2 = min(s2, p1), b3 = min(s3, p0);
        unsigned t0 = min(b0, b2), t2 = max(b0, b2), t1 = min(b1, b3), t3 = max(b1, b3);
        s0 = min(t0, t1); s1 = max(t0, t1); s2 = min(t2, t3); s3 = max(t2, t3);
        // merge level 2 (rq^2): exact top-4 of 64 (order irrelevant)
        p0 = (unsigned)__shfl_xor((int)s0, 2, 64);
        p1 = (unsigned)__shfl_xor((int)s1, 2, 64);
        p2 = (unsigned)__shfl_xor((int)s2, 2, 64);
        p3 = (unsigned)__shfl_xor((int)s3, 2, 64);
        b0 = min(s0, p3); b1 = min(s1, p2); b2 = min(s2, p1); b3 = min(s3, p0);
        if (rq == p) {
            *(uint4*)(cand_part + (size_t)(m0 + rrow) * ENT + blockIdx.x * 16 + p * 4) =
                make_uint4(b0, b1, b2, b3);
        }
        __syncthreads();
    }
}

// ---------------- fused select: scan 2048 keys -> exact top-16 -> fp32 rescore -> top-10 ----
// One block (4 waves) per row. Each wave extracts top-16 (round-7 lesson:
// per-wave cap must be >= global survivor count); wave 0 merges 64 -> exact
// top-16 of cand_part; exact fp32 rescore -> top-10.
__global__ __launch_bounds__(256) void knn_select_kernel(
        const unsigned* __restrict__ cand_part,  // [4096][ENT] packed keys
        const float* __restrict__ Q, const float* __restrict__ Mm,
        const float* __restrict__ mnorm,
        int* __restrict__ knn_idx) {
    const int row = blockIdx.x;
    const int wave = threadIdx.x >> 6, lane = threadIdx.x & 63;
    __shared__ unsigned sk[64];
    __shared__ int      sc[64];
    __shared__ int      ids[NCF];
    __shared__ float    d2s[NCF];

    // phase A: per-lane top-6 over this wave's 512 keys (8/lane, uint4 loads)
    unsigned ks[LK]; int ti[LK];
    #pragma unroll
    for (int q = 0; q < LK; ++q) { ks[q] = 0xFFFFFFFFu; ti[q] = IMAX; }
    const uint4* p4 = (const uint4*)(cand_part + (size_t)row * ENT) + wave * 128;
    #pragma unroll
    for (int i = 0; i < 2; ++i) {
        uint4 v = p4[lane + 64 * i];
        #pragma unroll
        for (int e = 0; e < 4; ++e) {
            unsigned k = (&v.x)[e];
            int pos = wave * 512 + (lane + 64 * i) * 4 + e;
            int gcol = (pos >> 3) * 128 + (int)(k & 127u);
            bool cm[LK];
            #pragma unroll
            for (int q = 0; q < LK; ++q) cm[q] = k < ks[q];
            #pragma unroll
            for (int q = LK - 1; q > 0; --q) {
                unsigned tns = cm[q] ? k : ks[q];  int tni = cm[q] ? gcol : ti[q];
                ks[q] = cm[q-1] ? ks[q-1] : tns;
                ti[q] = cm[q-1] ? ti[q-1] : tni;
            }
            ks[0] = cm[0] ? k : ks[0];
            ti[0] = cm[0] ? gcol : ti[0];
        }
    }
    // phase B: per-wave top-16 via argmin extraction
    #pragma unroll
    for (int r = 0; r < NCF; ++r) {
        unsigned mk = ks[0]; int mi = ti[0];
        #pragma unroll
        for (int off = 1; off < 64; off <<= 1) {
            unsigned ok = (unsigned)__shfl_xor((int)mk, off, 64);
            int      oi = __shfl_xor(mi, off, 64);
            bool t = (ok < mk) || (ok == mk && oi < mi);
            mk = t ? ok : mk; mi = t ? oi : mi;
        }
        bool win = (ks[0] == mk) && (ti[0] == mi);
        #pragma unroll
        for (int q = 0; q < LK - 1; ++q) {
            ks[q] = win ? ks[q+1] : ks[q];
            ti[q] = win ? ti[q+1] : ti[q];
        }
        ks[LK-1] = win ? 0xFFFFFFFFu : ks[LK-1];
        ti[LK-1] = win ? IMAX : ti[LK-1];
        if (lane == r) { sk[wave * NCF + r] = mk; sc[wave * NCF + r] = mi; }
    }
    __syncthreads();
    // phase C: wave 0 merges 64 -> exact top-16
    if (wave == 0) {
        unsigned myk = sk[lane];
        int      myc = sc[lane];
        #pragma unroll
        for (int r = 0; r < NCF; ++r) {
            unsigned mk = myk; int mi = myc;
            #pragma unroll
            for (int off = 1; off < 64; off <<= 1) {
                unsigned ok = (unsigned)__shfl_xor((int)mk, off, 64);
                int      oi = __shfl_xor(mi, off, 64);
                bool t = (ok < mk) || (ok == mk && oi < mi);
                mk = t ? ok : mk; mi = t ? oi : mi;
            }
            bool win = (myk == mk) && (myc == mi);
            myk = win ? 0xFFFFFFFFu : myk;
            myc = win ? IMAX : myc;
            if (lane == r) ids[r] = mi;
        }
    }
    __syncthreads();
    // phase D: exact fp32 rescore of 16 candidates
    float4 q0 = *(const float4*)(Q + (size_t)row * DD + lane * 8);
    float4 q1 = *(const float4*)(Q + (size_t)row * DD + lane * 8 + 4);
    for (int c = wave; c < NCF; c += 4) {
        int j = ids[c];
        const float* mr = Mm + (size_t)j * DD;
        float4 m0 = *(const float4*)(mr + lane * 8);
        float4 m1 = *(const float4*)(mr + lane * 8 + 4);
        float dot = q0.x*m0.x + q0.y*m0.y + q0.z*m0.z + q0.w*m0.w
                  + q1.x*m1.x + q1.y*m1.y + q1.z*m1.z + q1.w*m1.w;
        #pragma unroll
        for (int off = 32; off; off >>= 1) dot += __shfl_xor(dot, off, 64);
        if (lane == 0) d2s[c] = fmaf(-2.f, dot, mnorm[j]);
    }
    __syncthreads();
    // phase E: top-10 (exact lexicographic)
    if (threadIdx.x == 0) {
        float ts[TOPN]; int tj[TOPN];
        #pragma unroll
        for (int p = 0; p < TOPN; ++p) { ts[p] = FINF; tj[p] = IMAX; }
        for (int c = 0; c < NCF; ++c) topk_insert<TOPN>(ts, tj, d2s[c], ids[c]);
        #pragma unroll
        for (int p = 0; p < TOPN; ++p) knn_idx[row * TOPN + p] = tj[p];
    }
}

// ---------------- unified bf16 MFMA GEMM (m97 structure, swizzled LDS) ----------------
template<int ACT, int OUT_BF16>
__global__ __launch_bounds__(256) void gemm_bf16_nt(
        const unsigned short* __restrict__ A,
        const unsigned short* __restrict__ B,
        const float* __restrict__ bias,
        void* __restrict__ Cout, int ldc) {
    __shared__ __align__(16) unsigned short As[128 * 64];
    __shared__ __align__(16) unsigned short Bs[128 * 64];
    const int tid  = threadIdx.x;
    const int wave = tid >> 6, lane = tid & 63;
    const int quad = lane >> 4, c16 = lane & 15;
    const int m0 = blockIdx.y * 128, n0 = blockIdx.x * 128;
    const int wm0 = (wave >> 1) * 64, wn0 = (wave & 1) * 64;
    const int srow = wave * 32 + (lane >> 3);
    const int schunk = (lane & 7) ^ ((lane >> 3) & 7);
    const int xsw = c16 & 7;

    f32x4 acc[4][4] = {};

    for (int kt = 0; kt < DD; kt += 64) {
        __syncthreads();
        #pragma unroll
        for (int i = 0; i < 4; ++i) {
            const unsigned short* ga = A + (size_t)(m0 + srow + i * 8) * DD + kt + schunk * 8;
            async_copy16(ga, &As[(wave * 32 + i * 8) * 64]);
            const unsigned short* gb = B + (size_t)(n0 + srow + i * 8) * DD + kt + schunk * 8;
            async_copy16(gb, &Bs[(wave * 32 + i * 8) * 64]);
        }
        __syncthreads();
        #pragma unroll
        for (int ks = 0; ks < 64; ks += 32) {
            const int coff = (((ks >> 3) + quad) ^ xsw) << 3;
            bf16x8 af[4], bff[4];
            #pragma unroll
            for (int mt = 0; mt < 4; ++mt)
                af[mt] = *(const bf16x8*)&As[(wm0 + mt * 16 + c16) * 64 + coff];
            #pragma unroll
            for (int nt = 0; nt < 4; ++nt)
                bff[nt] = *(const bf16x8*)&Bs[(wn0 + nt * 16 + c16) * 64 + coff];
            #pragma unroll
            for (int mt = 0; mt < 4; ++mt)
                #pragma unroll
                for (int nt = 0; nt < 4; ++nt)
                    acc[mt][nt] = __builtin_amdgcn_mfma_f32_16x16x32_bf16(
                        af[mt], bff[nt], acc[mt][nt], 0, 0, 0);
        }
    }
    #pragma unroll
    for (int nt = 0; nt < 4; ++nt) {
        int ncol = n0 + wn0 + nt * 16 + c16;
        float bv = bias[ncol];
        #pragma unroll
        for (int mt = 0; mt < 4; ++mt) {
            size_t rbase = (size_t)(m0 + wm0 + mt * 16 + quad * 4) * ldc + ncol;
            #pragma unroll
            for (int r = 0; r < 4; ++r) {
                float v = acc[mt][nt][r] + bv;
                if (ACT == 1) v = v >= 0.f ? v : 0.01f * v;
                if (OUT_BF16) ((unsigned short*)Cout)[rbase + (size_t)r * ldc] = f2bf(v);
                else          ((float*)Cout)[rbase + (size_t)r * ldc] = v;
            }
        }
    }
}

// ---------------- K/V/q projections in ONE dispatch (compacted y-grid) ----------------
// y in [0,256) -> K; [256,512) -> V; [512,544) -> q.  No dead blocks.
struct G3 {
    const unsigned short* A[3];
    const unsigned short* B[3];
    const float* bias[3];
    void* C[3];
    int obf[3];
};
__global__ __launch_bounds__(256) void gemm3_kernel(G3 g) {
    const int yy = blockIdx.y;
    const int z = (yy >= 512) ? 2 : (yy >= 256 ? 1 : 0);
    const int my = yy - z * 256;
    __shared__ __align__(16) unsigned short As[128 * 64];
    __shared__ __align__(16) unsigned short Bs[128 * 64];
    const unsigned short* A = g.A[z];
    const unsigned short* B = g.B[z];
    const int tid  = threadIdx.x;
    const int wave = tid >> 6, lane = tid & 63;
    const int quad = lane >> 4, c16 = lane & 15;
    const int m0 = my * 128, n0 = blockIdx.x * 128;
    const int wm0 = (wave >> 1) * 64, wn0 = (wave & 1) * 64;
    const int srow = wave * 32 + (lane >> 3);
    const int schunk = (lane & 7) ^ ((lane >> 3) & 7);
    const int xsw = c16 & 7;

    f32x4 acc[4][4] = {};

    for (int kt = 0; kt < DD; kt += 64) {
        __syncthreads();
        #pragma unroll
        for (int i = 0; i < 4; ++i) {
            const unsigned short* ga = A + (size_t)(m0 + srow + i * 8) * DD + kt + schunk * 8;
            async_copy16(ga, &As[(wave * 32 + i * 8) * 64]);
            const unsigned short* gb = B + (size_t)(n0 + srow + i * 8) * DD + kt + schunk * 8;
            async_copy16(gb, &Bs[(wave * 32 + i * 8) * 64]);
        }
        __syncthreads();
        #pragma unroll
        for (int ks = 0; ks < 64; ks += 32) {
            const int coff = (((ks >> 3) + quad) ^ xsw) << 3;
            bf16x8 af[4], bff[4];
            #pragma unroll
            for (int mt = 0; mt < 4; ++mt)
                af[mt] = *(const bf16x8*)&As[(wm0 + mt * 16 + c16) * 64 + coff];
            #pragma unroll
            for (int nt = 0; nt < 4; ++nt)
                bff[nt] = *(const bf16x8*)&Bs[(wn0 + nt * 16 + c16) * 64 + coff];
            #pragma unroll
            for (int mt = 0; mt < 4; ++mt)
                #pragma unroll
                for (int nt = 0; nt < 4; ++nt)
                    acc[mt][nt] = __builtin_amdgcn_mfma_f32_16x16x32_bf16(
                        af[mt], bff[nt], acc[mt][nt], 0, 0, 0);
        }
    }
    const int obf = g.obf[z];
    #pragma unroll
    for (int nt = 0; nt < 4; ++nt) {
        int ncol = n0 + wn0 + nt * 16 + c16;
        float bv = g.bias[z][ncol];
        #pragma unroll
        for (int mt = 0; mt < 4; ++mt) {
            size_t rbase = (size_t)(m0 + wm0 + mt * 16 + quad * 4) * DD + ncol;
            #pragma unroll
            for (int r = 0; r < 4; ++r) {
                float v = acc[mt][nt][r] + bv;
                if (obf) ((unsigned short*)g.C[z])[rbase + (size_t)r * DD] = f2bf(v);
                else     ((float*)g.C[z])[rbase + (size_t)r * DD] = v;
            }
        }
    }
}

// ---------------- attention: one block per query row, one wave per head ----------------
__global__ __launch_bounds__(512) void attn_kernel(
        const float* __restrict__ qh, const unsigned short* __restrict__ Kall,
        const unsigned short* __restrict__ Vall, const int* __restrict__ knn_idx,
        unsigned short* __restrict__ ctx_b) {
    const int b = blockIdx.x;
    const int h = threadIdx.x >> 6;
    const int l = threadIdx.x & 63;
    const int col = (h << 6) + l;
    int idxs[TOPN];
    #pragma unroll
    for (int n = 0; n < TOPN; ++n) idxs[n] = knn_idx[b * TOPN + n];
    const float q = qh[(size_t)b * DD + col];
    float sc[TOPN];
    #pragma unroll
    for (int n = 0; n < TOPN; ++n) {
        float p = q * __uint_as_float((unsigned)Kall[(size_t)idxs[n] * DD + col] << 16);
        #pragma unroll
        for (int off = 32; off; off >>= 1) p += __shfl_xor(p, off, 64);
        sc[n] = p * 0.125f;
    }
    float mx = sc[0];
    #pragma unroll
    for (int n = 1; n < TOPN; ++n) mx = fmaxf(mx, sc[n]);
    float se = 0.f;
    #pragma unroll
    for (int n = 0; n < TOPN; ++n) { sc[n] = expf(sc[n] - mx); se += sc[n]; }
    const float inv = 1.f / se;
    float o = 0.f;
    #pragma unroll
    for (int n = 0; n < TOPN; ++n)
        o = fmaf(sc[n] * inv,
                 __uint_as_float((unsigned)Vall[(size_t)idxs[n] * DD + col] << 16), o);
    ctx_b[(size_t)b * DD + col] = f2bf(o);
}

// ---------------- residual add + layernorm (optional bf16 secondary output) ----------------
template<int EMIT_BF16>
__global__ __launch_bounds__(256) void add_ln_kernel(
        const float* __restrict__ X, const float* __restrict__ Y,
        const float* __restrict__ g, const float* __restrict__ be,
        float* __restrict__ out, unsigned short* __restrict__ out_b) {
    const int row = blockIdx.x;
    const int t = threadIdx.x;
    const size_t base = (size_t)row * DD;
    float v0 = X[base + t]       + Y[base + t];
    float v1 = X[base + 256 + t] + Y[base + 256 + t];
    float s = v0 + v1, sq = v0 * v0 + v1 * v1;
    #pragma unroll
    for (int off = 32; off; off >>= 1) { s += __shfl_xor(s, off, 64); sq += __shfl_xor(sq, off, 64); }
    __shared__ float rs[4], rq[4];
    const int w = t >> 6, l = t & 63;
    if (l == 0) { rs[w] = s; rq[w] = sq; }
    __syncthreads();
    float tot  = rs[0] + rs[1] + rs[2] + rs[3];
    float totq = rq[0] + rq[1] + rq[2] + rq[3];
    float mu = tot * (1.f / DD);
    float var = totq * (1.f / DD) - mu * mu;
    float rstd = rsqrtf(var + 1e-5f);
    float o0 = (v0 - mu) * rstd * g[t]       + be[t];
    float o1 = (v1 - mu) * rstd * g[256 + t] + be[256 + t];
    out[base + t] = o0;
    out[base + 256 + t] = o1;
    if (EMIT_BF16) {
        out_b[base + t] = f2bf(o0);
        out_b[base + 256 + t] = f2bf(o1);
    }
}

// ---------------- launch ----------------
extern "C" void kernel_launch(void* const* d_in, const int* in_sizes, int n_in,
                              void* d_out, int out_size, void* d_ws, size_t ws_size,
                              hipStream_t stream) {
    const float* visit = (const float*)d_in[0];
    const float* Epat  = (const float*)d_in[1];
    const float* Emed  = (const float*)d_in[2];
    const float* Wq = (const float*)d_in[3];
    const float* Wk = (const float*)d_in[4];
    const float* Wv = (const float*)d_in[5];
    const float* bq = (const float*)d_in[6];
    const float* bk = (const float*)d_in[7];
    const float* bv = (const float*)d_in[8];
    const float* Wo = (const float*)d_in[9];
    const float* bo = (const float*)d_in[10];
    const float* W1 = (const float*)d_in[11];
    const float* b1 = (const float*)d_in[12];
    const float* W2 = (const float*)d_in[13];
    const float* b2 = (const float*)d_in[14];
    const float* ln1g = (const float*)d_in[15];
    const float* ln1b = (const float*)d_in[16];
    const float* ln2g = (const float*)d_in[17];
    const float* ln2b = (const float*)d_in[18];
    float* out = (float*)d_out;

    // ---- workspace layout, ~174 MB peak ----
    char* base = (char*)d_ws;
    const size_t MB = 1u << 20;
    float* mnorm   = (float*)(base);                    // 128 KB
    float* msc     = (float*)(base + 256*1024);         // 128 KB (Epat row scales)
    float* qsc     = (float*)(base + 512*1024);         // 16 KB  (visit row scales)
    int*   knn_idx = (int*)  (base + 2*MB);             // 160 KB
    float* qh      = (float*)(base + 3*MB);             // 8 MB
    float* attn_o  = qh;                                // alias: qh dead after attn
    float* x1      = (float*)(base + 11*MB);            // 8 MB
    float* ff      = (float*)(base + 19*MB);            // 8 MB
    unsigned short* Qb    = (unsigned short*)(base + 27*MB);  // 4 MB (visit bf16)
    unsigned short* ctx_b = (unsigned short*)(base + 31*MB);  // 4 MB
    unsigned short* x1_b  = (unsigned short*)(base + 35*MB);  // 4 MB
    unsigned short* h1_b  = (unsigned short*)(base + 39*MB);  // 4 MB
    unsigned short* Wq_b  = (unsigned short*)(base + 43*MB);  // 6 x 512 KB
    unsigned short* Wk_b  = Wq_b + 262144;
    unsigned short* Wv_b  = Wk_b + 262144;
    unsigned short* Wo_b  = Wv_b + 262144;
    unsigned short* W1_b  = Wo_b + 262144;
    unsigned short* W2_b  = W1_b + 262144;
    unsigned short* Mb     = (unsigned short*)(base + 46*MB); // 32 MB (Epat bf16)
    unsigned short* Emed_b = (unsigned short*)(base + 78*MB); // 32 MB
    // K|V region (64 MB bf16); cand_part (32 MB) aliases Kall during kNN phase;
    // M8 (16 MB) + Q8 (2 MB) alias Vall (dead until gemm3).
    unsigned short* Kall = (unsigned short*)(base + 110*MB);  // 32 MB
    unsigned short* Vall = Kall + (size_t)NMEM * DD;          // 32 MB
    unsigned* cand_part = (unsigned*)Kall;                    // alias (kNN only)
    signed char* M8 = (signed char*)(base + 142*MB);          // alias Vall[0:16MB)
    signed char* Q8 = (signed char*)(base + 158*MB);          // alias Vall[16:18MB)

    // ---- casts + norms + int8 quant (2 dispatches total) ----
    cast_norm2_kernel<<<dim3(NMEM / 4, 3), 256, 0, stream>>>(
        Epat, Mb, Emed, Emed_b, visit, M8, Q8, mnorm, msc, qsc);
    CastDesc cd;
    cd.in[0] = visit; cd.out[0] = Qb;
    cd.in[1] = Wq; cd.in[2] = Wk; cd.in[3] = Wv; cd.in[4] = Wo; cd.in[5] = W1; cd.in[6] = W2;
    cd.out[1] = Wq_b; cd.out[2] = Wk_b; cd.out[3] = Wv_b; cd.out[4] = Wo_b; cd.out[5] = W1_b; cd.out[6] = W2_b;
    cd.start[0] = 0; cd.start[1] = 2048;
    for (int s = 2; s <= 7; ++s) cd.start[s] = cd.start[s-1] + 256;
    cast_multi_kernel<<<cd.start[7], 256, 0, stream>>>(cd);

    // ---- kNN: int8 MFMA scores + selection -> fused merge+rescore ----
    gemm_knn_kernel<<<dim3(NBX, BQ / 128), 512, 0, stream>>>(Q8, M8, mnorm, msc, qsc, cand_part);
    knn_select_kernel<<<BQ, 256, 0, stream>>>(cand_part, visit, Epat, mnorm, knn_idx);

    // ---- K/V/q projections in one compacted dispatch (Kall write overwrites cand_part;
    //      Vall write overwrites M8/Q8 — both dead by then)
    G3 g3;
    g3.A[0] = Mb;     g3.B[0] = Wk_b; g3.bias[0] = bk; g3.C[0] = Kall; g3.obf[0] = 1;
    g3.A[1] = Emed_b; g3.B[1] = Wv_b; g3.bias[1] = bv; g3.C[1] = Vall; g3.obf[1] = 1;
    g3.A[2] = Qb;     g3.B[2] = Wq_b; g3.bias[2] = bq; g3.C[2] = qh;   g3.obf[2] = 0;
    gemm3_kernel<<<dim3(4, 544), 256, 0, stream>>>(g3);

    attn_kernel<<<BQ, 512, 0, stream>>>(qh, Kall, Vall, knn_idx, ctx_b);

    gemm_bf16_nt<0,0><<<dim3(4, BQ / 128), 256, 0, stream>>>(ctx_b, Wo_b, bo, attn_o, DD);
    add_ln_kernel<1><<<BQ, 256, 0, stream>>>(visit, attn_o, ln1g, ln1b, x1, x1_b);
    gemm_bf16_nt<1,1><<<dim3(4, BQ / 128), 256, 0, stream>>>(x1_b, W1_b, b1, h1_b, DD);
    gemm_bf16_nt<0,0><<<dim3(4, BQ / 128), 256, 0, stream>>>(h1_b, W2_b, b2, ff,   DD);
    add_ln_kernel<0><<<BQ, 256, 0, stream>>>(x1, ff, ln2g, ln2b, out, nullptr);
}

// Round 6
// 495.275 us; speedup vs baseline: 1.5490x; 1.0824x over previous
//
#include <hip/hip_runtime.h>
#include <math.h>

#define BQ 4096
#define NMEM 32768
#define DD 512
#define TOPN 10
#define NBX 128                  /* 256-row mem blocks over NMEM */
#define ENT 2048                 /* candidate entries per row = NBX*16 */
#define NCF 16                   /* final candidates per row */
#define LK 6                     /* per-lane top-K in knn_select scan */
#define FINF 3.402823466e+38f
#define IMAX 0x7fffffff

typedef __attribute__((ext_vector_type(8))) short    bf16x8;
typedef __attribute__((ext_vector_type(4))) float    f32x4;
typedef __attribute__((ext_vector_type(4))) int      i32x4;

// ---------------- helpers ----------------
__device__ __forceinline__ unsigned short f2bf(float x) {
    unsigned int u = __float_as_uint(x);
    u += 0x7fffu + ((u >> 16) & 1u);          // round-to-nearest-even
    return (unsigned short)(u >> 16);
}
__device__ __forceinline__ void async_copy16(const void* gp, void* lp) {
    __builtin_amdgcn_global_load_lds(
        (const __attribute__((address_space(1))) void*)gp,
        (__attribute__((address_space(3))) void*)lp, 16, 0, 0);
}
__device__ __forceinline__ bool lt_si(float s, int j, float s2, int j2) {
    return (s < s2) || (s == s2 && j < j2);   // matches top_k tie-break
}
template<int KN>
__device__ __forceinline__ void topk_insert(float (&ts)[KN], int (&ti)[KN], float s, int j) {
    if (!lt_si(s, j, ts[KN-1], ti[KN-1])) return;
    #pragma unroll
    for (int p = KN-1; p > 0; --p) {
        if (lt_si(s, j, ts[p-1], ti[p-1])) { ts[p] = ts[p-1]; ti[p] = ti[p-1]; }
        else { ts[p] = s; ti[p] = j; return; }
    }
    ts[0] = s; ti[0] = j;
}

// ---------------- segmented cast: visit + 6 weight matrices in ONE dispatch ----------------
struct CastDesc {
    const float* in[7];
    unsigned short* out[7];
    int start[8];   // cumulative block starts, start[7] = total
};
__global__ __launch_bounds__(256) void cast_multi_kernel(CastDesc d) {
    int blk = blockIdx.x;
    int seg = 0;
    #pragma unroll
    for (int s = 0; s < 6; ++s) seg += (blk >= d.start[s + 1]) ? 1 : 0;
    int local = blk - d.start[seg];
    int i = (local * 256 + threadIdx.x) * 4;
    float4 v = *(const float4*)(d.in[seg] + i);
    ushort4 o;
    o.x = f2bf(v.x); o.y = f2bf(v.y); o.z = f2bf(v.z); o.w = f2bf(v.w);
    *(ushort4*)(d.out[seg] + i) = o;
}

// ---------------- fused cast planes over Epat/Emed/visit ----------------
// y==0: Epat -> bf16 + int8(+scale) + ||row||^2 ; y==1: Emed -> bf16 ;
// y==2 (x<1024): visit -> int8(+scale).
// int8 quant: per-row symmetric absmax/127 (d2-error std ~0.5 vs rank
// spacing ~0.45/rank; survivors rescored exact fp32 -> selection-safe).
__global__ __launch_bounds__(256) void cast_norm2_kernel(
        const float* __restrict__ inA, unsigned short* __restrict__ outA,
        const float* __restrict__ inB, unsigned short* __restrict__ outB,
        const float* __restrict__ inV,
        signed char* __restrict__ outA8, signed char* __restrict__ outV8,
        float* __restrict__ mnorm, float* __restrict__ msc,
        float* __restrict__ qsc) {
    const int pl = blockIdx.y;
    if (pl == 2 && blockIdx.x >= BQ / 4) return;
    const float* in = (pl == 0) ? inA : (pl == 1 ? inB : inV);
    int row = blockIdx.x * 4 + (threadIdx.x >> 6);
    int lane = threadIdx.x & 63;
    const float* r = in + (size_t)row * DD + lane * 8;
    float4 a = *(const float4*)r;
    float4 b = *(const float4*)(r + 4);
    if (pl < 2) {
        unsigned short* out = pl ? outB : outA;
        ushort4 oa, ob;
        oa.x = f2bf(a.x); oa.y = f2bf(a.y); oa.z = f2bf(a.z); oa.w = f2bf(a.w);
        ob.x = f2bf(b.x); ob.y = f2bf(b.y); ob.z = f2bf(b.z); ob.w = f2bf(b.w);
        unsigned short* op = out + (size_t)row * DD + lane * 8;
        *(ushort4*)op = oa; *(ushort4*)(op + 4) = ob;
    }
    if (pl != 1) {
        float ax = fmaxf(fmaxf(fmaxf(fabsf(a.x), fabsf(a.y)), fmaxf(fabsf(a.z), fabsf(a.w))),
                         fmaxf(fmaxf(fabsf(b.x), fabsf(b.y)), fmaxf(fabsf(b.z), fabsf(b.w))));
        float s = a.x*a.x + a.y*a.y + a.z*a.z + a.w*a.w
                + b.x*b.x + b.y*b.y + b.z*b.z + b.w*b.w;
        #pragma unroll
        for (int off = 32; off; off >>= 1) {
            ax = fmaxf(ax, __shfl_xor(ax, off, 64));
            if (pl == 0) s += __shfl_xor(s, off, 64);
        }
        ax = fmaxf(ax, 1e-30f);
        float inv = 127.0f / ax;
        int q[8];
        q[0] = __float2int_rn(a.x*inv); q[1] = __float2int_rn(a.y*inv);
        q[2] = __float2int_rn(a.z*inv); q[3] = __float2int_rn(a.w*inv);
        q[4] = __float2int_rn(b.x*inv); q[5] = __float2int_rn(b.y*inv);
        q[6] = __float2int_rn(b.z*inv); q[7] = __float2int_rn(b.w*inv);
        unsigned w0 = (q[0]&255) | ((q[1]&255)<<8) | ((q[2]&255)<<16) | ((unsigned)(q[3]&255)<<24);
        unsigned w1 = (q[4]&255) | ((q[5]&255)<<8) | ((q[6]&255)<<16) | ((unsigned)(q[7]&255)<<24);
        signed char* o8 = (pl == 0 ? outA8 : outV8) + (size_t)row * DD + lane * 8;
        *(uint2*)o8 = make_uint2(w0, w1);
        if (lane == 0) {
            if (pl == 0) { mnorm[row] = s; msc[row] = ax * (1.0f/127.0f); }
            else         { qsc[row] = ax * (1.0f/127.0f); }
        }
    }
}

// ======== Round-15: swapped-operand int8 kNN GEMM — register-local selection ========
// r5 post-mortem: 355K cyc/CU; VALU 153K (43%) dominated by the LDS-S epilogue
// (per score: pack + S-write + S-read + 8-op insert + 8 barriers/block +
// 8.4e6 conflict cycles). Fix: swap MFMA operands (A=M8 mem rows, B=Q8
// queries). C-layout then gives each lane 16 mem-row scores (mt x r) of ONE
// query (nt,c16) — the selection axis is register-local:
//   pack -> sort4 (5 comparators) -> bitonic merge (10 ops/4 keys)
//   -> 2 shfl_xor levels across quads (r4/r5-verified merge sequence)
//   -> predicated uint4 store. No S overlay, no epilogue barriers.
// K-loop datapath byte-identical to r5 (staging, swizzle, schedule); only
// the A/B pointer roles swap. Block: 256 mem x 128 queries; wave-tile 64x64
// (wmem=wave>>1 in [0,4), wq=wave&1). cand_part layout/decode bit-compatible:
// slot wmem*4, key low7 = (wmem&1)*64 + mt*16+quad*4+r.
__global__ __launch_bounds__(512, 4) void gemm_knn_kernel(
        const signed char* __restrict__ Q8,   // [4096][512] i8
        const signed char* __restrict__ M8,   // [NMEM][512] i8
        const float* __restrict__ mnorm, const float* __restrict__ msc,
        const float* __restrict__ qsc,
        unsigned* __restrict__ cand_part) {   // [4096][ENT] packed keys
    __shared__ __align__(16) struct {
        signed char A[2][256][64];   // mem rows (ring-2)   32 KB
        signed char B[2][128][64];   // query rows (ring-2) 16 KB
    } sh;
    __shared__ float tb_mn[256], tb_ms2[256], qsl[128];
    const int tid  = threadIdx.x;
    const int lane = tid & 63;
    const int wave = tid >> 6;
    const int quad = lane >> 4, c16 = lane & 15;
    const int wmem = wave >> 1, wq = wave & 1;        // 4 mem-groups x 2 query-groups
    const int mb0 = blockIdx.x * 256;                 // mem-row base
    const int q0  = blockIdx.y * 128;                 // query-row base
    // staging identity: 512 threads = 128 rows x 4 chunks of 16B
    const int srow   = tid >> 2;                      // [0,128)
    const int schunk = (tid & 3) ^ ((tid >> 3) & 3);  // pre-swizzled source chunk
    const signed char* ag = M8 + (size_t)(mb0 + srow) * DD + schunk * 16;
    const signed char* bg = Q8 + (size_t)(q0 + srow) * DD + schunk * 16;
    const int cq = (quad ^ ((c16 >> 1) & 3)) * 16;    // reader chunk (swizzled), bytes

    i32x4 acc[4][4] = {};
    i32x4 af[4], bf[4];

    if (tid < 256)      { tb_mn[tid] = mnorm[mb0 + tid]; tb_ms2[tid] = -2.0f * msc[mb0 + tid]; }
    else if (tid < 384) { qsl[tid - 256] = qsc[q0 + tid - 256]; }

#define STG(tt) do {                                                            \
    const int s_ = (tt) & 1;                                                    \
    async_copy16(ag + (size_t)(tt)*64,            &sh.A[s_][srow][(tid & 3) * 16]);      \
    async_copy16(ag + (size_t)(tt)*64 + 128*DD,   &sh.A[s_][128 + srow][(tid & 3) * 16]);\
    async_copy16(bg + (size_t)(tt)*64,            &sh.B[s_][srow][(tid & 3) * 16]);      \
} while (0)
#define RD(tt) do {                                                             \
    const int s_ = (tt) & 1;                                                    \
    _Pragma("unroll")                                                           \
    for (int mt = 0; mt < 4; ++mt)                                              \
        af[mt] = *(const i32x4*)&sh.A[s_][wmem*64 + mt*16 + c16][cq];           \
    _Pragma("unroll")                                                           \
    for (int nt = 0; nt < 4; ++nt)                                              \
        bf[nt] = *(const i32x4*)&sh.B[s_][wq*64 + nt*16 + c16][cq];             \
} while (0)
#define MM() do {                                                               \
    _Pragma("unroll")                                                           \
    for (int mt = 0; mt < 4; ++mt)                                              \
        _Pragma("unroll")                                                       \
        for (int nt = 0; nt < 4; ++nt)                                          \
            acc[mt][nt] = __builtin_amdgcn_mfma_i32_16x16x64_i8(                \
                af[mt], bf[nt], acc[mt][nt], 0, 0, 0);                          \
} while (0)

    // prologue: stage tile 0, drain, barrier (also publishes the tables)
    STG(0);
    asm volatile("s_waitcnt vmcnt(0)" ::: "memory");
    __builtin_amdgcn_s_barrier();
    __builtin_amdgcn_sched_barrier(0);

    #pragma unroll
    for (int t = 0; t < 8; ++t) {
        RD(t);
        if (t < 7) STG(t + 1);
        __builtin_amdgcn_sched_barrier(0);
        asm volatile("s_waitcnt lgkmcnt(0)" ::: "memory");
        __builtin_amdgcn_sched_barrier(0);
        __builtin_amdgcn_s_setprio(1);
        MM();
        __builtin_amdgcn_s_setprio(0);
        __builtin_amdgcn_sched_barrier(0);
        asm volatile("s_waitcnt vmcnt(0)" ::: "memory");   // t+1 landed (under MFMA)
        __builtin_amdgcn_sched_barrier(0);
        __builtin_amdgcn_s_barrier();
    }
#undef STG
#undef RD
#undef MM

    // ---- register-local selection: top-4 per 64-mem-group per query ----
    // Lane owns 16 scores (mt x r = mem rows wmem*64+mt*16+quad*4+r) of query
    // (q0 + wq*64 + nt*16 + c16). sort4 + bitonic running-merge -> sorted-4;
    // shfl_xor 16/32 merges the 4 quads (each wave's 64 mem rows = one group).
    #pragma unroll
    for (int nt = 0; nt < 4; ++nt) {
        float qv = qsl[wq*64 + nt*16 + c16];
        unsigned s0, s1, s2, s3;
        #pragma unroll
        for (int mt = 0; mt < 4; ++mt) {
            unsigned k0, k1, k2, k3, lo, hi;
            {
                unsigned kk[4];
                #pragma unroll
                for (int r = 0; r < 4; ++r) {
                    int mrow = wmem*64 + mt*16 + quad*4 + r;
                    float s = fmaxf(fmaf(tb_ms2[mrow] * qv, (float)acc[mt][nt][r], tb_mn[mrow]), 0.f);
                    kk[r] = (__float_as_uint(s) & 0xFFFFFF80u)
                          | (unsigned)(((wmem & 1) << 6) | (mt*16 + quad*4 + r));
                }
                k0 = kk[0]; k1 = kk[1]; k2 = kk[2]; k3 = kk[3];
            }
            // sort4 ascending: (0,1)(2,3)(0,2)(1,3)(1,2)
            lo = min(k0,k1); hi = max(k0,k1); k0 = lo; k1 = hi;
            lo = min(k2,k3); hi = max(k2,k3); k2 = lo; k3 = hi;
            lo = min(k0,k2); hi = max(k0,k2); k0 = lo; k2 = hi;
            lo = min(k1,k3); hi = max(k1,k3); k1 = lo; k3 = hi;
            lo = min(k1,k2); hi = max(k1,k2); k1 = lo; k2 = hi;
            if (mt == 0) { s0 = k0; s1 = k1; s2 = k2; s3 = k3; }
            else {
                unsigned b0 = min(s0,k3), b1 = min(s1,k2), b2 = min(s2,k1), b3 = min(s3,k0);
                unsigned t0 = min(b0,b2), t2 = max(b0,b2), t1 = min(b1,b3), t3 = max(b1,b3);
                s0 = min(t0,t1); s1 = max(t0,t1); s2 = min(t2,t3); s3 = max(t2,t3);
            }
        }
        // merge quads: level 1 (quad^1), resort; level 2 (quad^2), final set
        unsigned p0, p1, p2, p3, b0, b1, b2, b3, t0, t1, t2, t3;
        p0 = (unsigned)__shfl_xor((int)s0, 16, 64);
        p1 = (unsigned)__shfl_xor((int)s1, 16, 64);
        p2 = (unsigned)__shfl_xor((int)s2, 16, 64);
        p3 = (unsigned)__shfl_xor((int)s3, 16, 64);
        b0 = min(s0,p3); b1 = min(s1,p2); b2 = min(s2,p1); b3 = min(s3,p0);
        t0 = min(b0,b2); t2 = max(b0,b2); t1 = min(b1,b3); t3 = max(b1,b3);
        s0 = min(t0,t1); s1 = max(t0,t1); s2 = min(t2,t3); s3 = max(t2,t3);
        p0 = (unsigned)__shfl_xor((int)s0, 32, 64);
        p1 = (unsigned)__shfl_xor((int)s1, 32, 64);
        p2 = (unsigned)__shfl_xor((int)s2, 32, 64);
        p3 = (unsigned)__shfl_xor((int)s3, 32, 64);
        b0 = min(s0,p3); b1 = min(s1,p2); b2 = min(s2,p1); b3 = min(s3,p0);
        if (quad == 0) {
            *(uint4*)(cand_part + (size_t)(q0 + wq*64 + nt*16 + c16) * ENT
                      + blockIdx.x * 16 + wmem * 4) = make_uint4(b0, b1, b2, b3);
        }
    }
}

// ---------------- fused select: scan 2048 keys -> exact top-16 -> fp32 rescore -> top-10 ----
// One block (4 waves) per row. Each wave extracts top-16 (round-7 lesson:
// per-wave cap must be >= global survivor count); wave 0 merges 64 -> exact
// top-16 of cand_part; exact fp32 rescore -> top-10.
__global__ __launch_bounds__(256) void knn_select_kernel(
        const unsigned* __restrict__ cand_part,  // [4096][ENT] packed keys
        const float* __restrict__ Q, const float* __restrict__ Mm,
        const float* __restrict__ mnorm,
        int* __restrict__ knn_idx) {
    const int row = blockIdx.x;
    const int wave = threadIdx.x >> 6, lane = threadIdx.x & 63;
    __shared__ unsigned sk[64];
    __shared__ int      sc[64];
    __shared__ int      ids[NCF];
    __shared__ float    d2s[NCF];

    // phase A: per-lane top-6 over this wave's 512 keys (8/lane, uint4 loads)
    unsigned ks[LK]; int ti[LK];
    #pragma unroll
    for (int q = 0; q < LK; ++q) { ks[q] = 0xFFFFFFFFu; ti[q] = IMAX; }
    const uint4* p4 = (const uint4*)(cand_part + (size_t)row * ENT) + wave * 128;
    #pragma unroll
    for (int i = 0; i < 2; ++i) {
        uint4 v = p4[lane + 64 * i];
        #pragma unroll
        for (int e = 0; e < 4; ++e) {
            unsigned k = (&v.x)[e];
            int pos = wave * 512 + (lane + 64 * i) * 4 + e;
            int gcol = (pos >> 3) * 128 + (int)(k & 127u);
            bool cm[LK];
            #pragma unroll
            for (int q = 0; q < LK; ++q) cm[q] = k < ks[q];
            #pragma unroll
            for (int q = LK - 1; q > 0; --q) {
                unsigned tns = cm[q] ? k : ks[q];  int tni = cm[q] ? gcol : ti[q];
                ks[q] = cm[q-1] ? ks[q-1] : tns;
                ti[q] = cm[q-1] ? ti[q-1] : tni;
            }
            ks[0] = cm[0] ? k : ks[0];
            ti[0] = cm[0] ? gcol : ti[0];
        }
    }
    // phase B: per-wave top-16 via argmin extraction
    #pragma unroll
    for (int r = 0; r < NCF; ++r) {
        unsigned mk = ks[0]; int mi = ti[0];
        #pragma unroll
        for (int off = 1; off < 64; off <<= 1) {
            unsigned ok = (unsigned)__shfl_xor((int)mk, off, 64);
            int      oi = __shfl_xor(mi, off, 64);
            bool t = (ok < mk) || (ok == mk && oi < mi);
            mk = t ? ok : mk; mi = t ? oi : mi;
        }
        bool win = (ks[0] == mk) && (ti[0] == mi);
        #pragma unroll
        for (int q = 0; q < LK - 1; ++q) {
            ks[q] = win ? ks[q+1] : ks[q];
            ti[q] = win ? ti[q+1] : ti[q];
        }
        ks[LK-1] = win ? 0xFFFFFFFFu : ks[LK-1];
        ti[LK-1] = win ? IMAX : ti[LK-1];
        if (lane == r) { sk[wave * NCF + r] = mk; sc[wave * NCF + r] = mi; }
    }
    __syncthreads();
    // phase C: wave 0 merges 64 -> exact top-16
    if (wave == 0) {
        unsigned myk = sk[lane];
        int      myc = sc[lane];
        #pragma unroll
        for (int r = 0; r < NCF; ++r) {
            unsigned mk = myk; int mi = myc;
            #pragma unroll
            for (int off = 1; off < 64; off <<= 1) {
                unsigned ok = (unsigned)__shfl_xor((int)mk, off, 64);
                int      oi = __shfl_xor(mi, off, 64);
                bool t = (ok < mk) || (ok == mk && oi < mi);
                mk = t ? ok : mk; mi = t ? oi : mi;
            }
            bool win = (myk == mk) && (myc == mi);
            myk = win ? 0xFFFFFFFFu : myk;
            myc = win ? IMAX : myc;
            if (lane == r) ids[r] = mi;
        }
    }
    __syncthreads();
    // phase D: exact fp32 rescore of 16 candidates
    float4 q0 = *(const float4*)(Q + (size_t)row * DD + lane * 8);
    float4 q1 = *(const float4*)(Q + (size_t)row * DD + lane * 8 + 4);
    for (int c = wave; c < NCF; c += 4) {
        int j = ids[c];
        const float* mr = Mm + (size_t)j * DD;
        float4 m0 = *(const float4*)(mr + lane * 8);
        float4 m1 = *(const float4*)(mr + lane * 8 + 4);
        float dot = q0.x*m0.x + q0.y*m0.y + q0.z*m0.z + q0.w*m0.w
                  + q1.x*m1.x + q1.y*m1.y + q1.z*m1.z + q1.w*m1.w;
        #pragma unroll
        for (int off = 32; off; off >>= 1) dot += __shfl_xor(dot, off, 64);
        if (lane == 0) d2s[c] = fmaf(-2.f, dot, mnorm[j]);
    }
    __syncthreads();
    // phase E: top-10 (exact lexicographic)
    if (threadIdx.x == 0) {
        float ts[TOPN]; int tj[TOPN];
        #pragma unroll
        for (int p = 0; p < TOPN; ++p) { ts[p] = FINF; tj[p] = IMAX; }
        for (int c = 0; c < NCF; ++c) topk_insert<TOPN>(ts, tj, d2s[c], ids[c]);
        #pragma unroll
        for (int p = 0; p < TOPN; ++p) knn_idx[row * TOPN + p] = tj[p];
    }
}

// ---------------- unified bf16 MFMA GEMM (m97 structure, swizzled LDS) ----------------
template<int ACT, int OUT_BF16>
__global__ __launch_bounds__(256) void gemm_bf16_nt(
        const unsigned short* __restrict__ A,
        const unsigned short* __restrict__ B,
        const float* __restrict__ bias,
        void* __restrict__ Cout, int ldc) {
    __shared__ __align__(16) unsigned short As[128 * 64];
    __shared__ __align__(16) unsigned short Bs[128 * 64];
    const int tid  = threadIdx.x;
    const int wave = tid >> 6, lane = tid & 63;
    const int quad = lane >> 4, c16 = lane & 15;
    const int m0 = blockIdx.y * 128, n0 = blockIdx.x * 128;
    const int wm0 = (wave >> 1) * 64, wn0 = (wave & 1) * 64;
    const int srow = wave * 32 + (lane >> 3);
    const int schunk = (lane & 7) ^ ((lane >> 3) & 7);
    const int xsw = c16 & 7;

    f32x4 acc[4][4] = {};

    for (int kt = 0; kt < DD; kt += 64) {
        __syncthreads();
        #pragma unroll
        for (int i = 0; i < 4; ++i) {
            const unsigned short* ga = A + (size_t)(m0 + srow + i * 8) * DD + kt + schunk * 8;
            async_copy16(ga, &As[(wave * 32 + i * 8) * 64]);
            const unsigned short* gb = B + (size_t)(n0 + srow + i * 8) * DD + kt + schunk * 8;
            async_copy16(gb, &Bs[(wave * 32 + i * 8) * 64]);
        }
        __syncthreads();
        #pragma unroll
        for (int ks = 0; ks < 64; ks += 32) {
            const int coff = (((ks >> 3) + quad) ^ xsw) << 3;
            bf16x8 af[4], bff[4];
            #pragma unroll
            for (int mt = 0; mt < 4; ++mt)
                af[mt] = *(const bf16x8*)&As[(wm0 + mt * 16 + c16) * 64 + coff];
            #pragma unroll
            for (int nt = 0; nt < 4; ++nt)
                bff[nt] = *(const bf16x8*)&Bs[(wn0 + nt * 16 + c16) * 64 + coff];
            #pragma unroll
            for (int mt = 0; mt < 4; ++mt)
                #pragma unroll
                for (int nt = 0; nt < 4; ++nt)
                    acc[mt][nt] = __builtin_amdgcn_mfma_f32_16x16x32_bf16(
                        af[mt], bff[nt], acc[mt][nt], 0, 0, 0);
        }
    }
    #pragma unroll
    for (int nt = 0; nt < 4; ++nt) {
        int ncol = n0 + wn0 + nt * 16 + c16;
        float bv = bias[ncol];
        #pragma unroll
        for (int mt = 0; mt < 4; ++mt) {
            size_t rbase = (size_t)(m0 + wm0 + mt * 16 + quad * 4) * ldc + ncol;
            #pragma unroll
            for (int r = 0; r < 4; ++r) {
                float v = acc[mt][nt][r] + bv;
                if (ACT == 1) v = v >= 0.f ? v : 0.01f * v;
                if (OUT_BF16) ((unsigned short*)Cout)[rbase + (size_t)r * ldc] = f2bf(v);
                else          ((float*)Cout)[rbase + (size_t)r * ldc] = v;
            }
        }
    }
}

// ---------------- K/V/q projections in ONE dispatch (compacted y-grid) ----------------
// y in [0,256) -> K; [256,512) -> V; [512,544) -> q.  No dead blocks.
struct G3 {
    const unsigned short* A[3];
    const unsigned short* B[3];
    const float* bias[3];
    void* C[3];
    int obf[3];
};
__global__ __launch_bounds__(256) void gemm3_kernel(G3 g) {
    const int yy = blockIdx.y;
    const int z = (yy >= 512) ? 2 : (yy >= 256 ? 1 : 0);
    const int my = yy - z * 256;
    __shared__ __align__(16) unsigned short As[128 * 64];
    __shared__ __align__(16) unsigned short Bs[128 * 64];
    const unsigned short* A = g.A[z];
    const unsigned short* B = g.B[z];
    const int tid  = threadIdx.x;
    const int wave = tid >> 6, lane = tid & 63;
    const int quad = lane >> 4, c16 = lane & 15;
    const int m0 = my * 128, n0 = blockIdx.x * 128;
    const int wm0 = (wave >> 1) * 64, wn0 = (wave & 1) * 64;
    const int srow = wave * 32 + (lane >> 3);
    const int schunk = (lane & 7) ^ ((lane >> 3) & 7);
    const int xsw = c16 & 7;

    f32x4 acc[4][4] = {};

    for (int kt = 0; kt < DD; kt += 64) {
        __syncthreads();
        #pragma unroll
        for (int i = 0; i < 4; ++i) {
            const unsigned short* ga = A + (size_t)(m0 + srow + i * 8) * DD + kt + schunk * 8;
            async_copy16(ga, &As[(wave * 32 + i * 8) * 64]);
            const unsigned short* gb = B + (size_t)(n0 + srow + i * 8) * DD + kt + schunk * 8;
            async_copy16(gb, &Bs[(wave * 32 + i * 8) * 64]);
        }
        __syncthreads();
        #pragma unroll
        for (int ks = 0; ks < 64; ks += 32) {
            const int coff = (((ks >> 3) + quad) ^ xsw) << 3;
            bf16x8 af[4], bff[4];
            #pragma unroll
            for (int mt = 0; mt < 4; ++mt)
                af[mt] = *(const bf16x8*)&As[(wm0 + mt * 16 + c16) * 64 + coff];
            #pragma unroll
            for (int nt = 0; nt < 4; ++nt)
                bff[nt] = *(const bf16x8*)&Bs[(wn0 + nt * 16 + c16) * 64 + coff];
            #pragma unroll
            for (int mt = 0; mt < 4; ++mt)
                #pragma unroll
                for (int nt = 0; nt < 4; ++nt)
                    acc[mt][nt] = __builtin_amdgcn_mfma_f32_16x16x32_bf16(
                        af[mt], bff[nt], acc[mt][nt], 0, 0, 0);
        }
    }
    const int obf = g.obf[z];
    #pragma unroll
    for (int nt = 0; nt < 4; ++nt) {
        int ncol = n0 + wn0 + nt * 16 + c16;
        float bv = g.bias[z][ncol];
        #pragma unroll
        for (int mt = 0; mt < 4; ++mt) {
            size_t rbase = (size_t)(m0 + wm0 + mt * 16 + quad * 4) * DD + ncol;
            #pragma unroll
            for (int r = 0; r < 4; ++r) {
                float v = acc[mt][nt][r] + bv;
                if (obf) ((unsigned short*)g.C[z])[rbase + (size_t)r * DD] = f2bf(v);
                else     ((float*)g.C[z])[rbase + (size_t)r * DD] = v;
            }
        }
    }
}

// ---------------- attention: one block per query row, one wave per head ----------------
__global__ __launch_bounds__(512) void attn_kernel(
        const float* __restrict__ qh, const unsigned short* __restrict__ Kall,
        const unsigned short* __restrict__ Vall, const int* __restrict__ knn_idx,
        unsigned short* __restrict__ ctx_b) {
    const int b = blockIdx.x;
    const int h = threadIdx.x >> 6;
    const int l = threadIdx.x & 63;
    const int col = (h << 6) + l;
    int idxs[TOPN];
    #pragma unroll
    for (int n = 0; n < TOPN; ++n) idxs[n] = knn_idx[b * TOPN + n];
    const float q = qh[(size_t)b * DD + col];
    float sc[TOPN];
    #pragma unroll
    for (int n = 0; n < TOPN; ++n) {
        float p = q * __uint_as_float((unsigned)Kall[(size_t)idxs[n] * DD + col] << 16);
        #pragma unroll
        for (int off = 32; off; off >>= 1) p += __shfl_xor(p, off, 64);
        sc[n] = p * 0.125f;
    }
    float mx = sc[0];
    #pragma unroll
    for (int n = 1; n < TOPN; ++n) mx = fmaxf(mx, sc[n]);
    float se = 0.f;
    #pragma unroll
    for (int n = 0; n < TOPN; ++n) { sc[n] = expf(sc[n] - mx); se += sc[n]; }
    const float inv = 1.f / se;
    float o = 0.f;
    #pragma unroll
    for (int n = 0; n < TOPN; ++n)
        o = fmaf(sc[n] * inv,
                 __uint_as_float((unsigned)Vall[(size_t)idxs[n] * DD + col] << 16), o);
    ctx_b[(size_t)b * DD + col] = f2bf(o);
}

// ---------------- residual add + layernorm (optional bf16 secondary output) ----------------
template<int EMIT_BF16>
__global__ __launch_bounds__(256) void add_ln_kernel(
        const float* __restrict__ X, const float* __restrict__ Y,
        const float* __restrict__ g, const float* __restrict__ be,
        float* __restrict__ out, unsigned short* __restrict__ out_b) {
    const int row = blockIdx.x;
    const int t = threadIdx.x;
    const size_t base = (size_t)row * DD;
    float v0 = X[base + t]       + Y[base + t];
    float v1 = X[base + 256 + t] + Y[base + 256 + t];
    float s = v0 + v1, sq = v0 * v0 + v1 * v1;
    #pragma unroll
    for (int off = 32; off; off >>= 1) { s += __shfl_xor(s, off, 64); sq += __shfl_xor(sq, off, 64); }
    __shared__ float rs[4], rq[4];
    const int w = t >> 6, l = t & 63;
    if (l == 0) { rs[w] = s; rq[w] = sq; }
    __syncthreads();
    float tot  = rs[0] + rs[1] + rs[2] + rs[3];
    float totq = rq[0] + rq[1] + rq[2] + rq[3];
    float mu = tot * (1.f / DD);
    float var = totq * (1.f / DD) - mu * mu;
    float rstd = rsqrtf(var + 1e-5f);
    float o0 = (v0 - mu) * rstd * g[t]       + be[t];
    float o1 = (v1 - mu) * rstd * g[256 + t] + be[256 + t];
    out[base + t] = o0;
    out[base + 256 + t] = o1;
    if (EMIT_BF16) {
        out_b[base + t] = f2bf(o0);
        out_b[base + 256 + t] = f2bf(o1);
    }
}

// ---------------- launch ----------------
extern "C" void kernel_launch(void* const* d_in, const int* in_sizes, int n_in,
                              void* d_out, int out_size, void* d_ws, size_t ws_size,
                              hipStream_t stream) {
    const float* visit = (const float*)d_in[0];
    const float* Epat  = (const float*)d_in[1];
    const float* Emed  = (const float*)d_in[2];
    const float* Wq = (const float*)d_in[3];
    const float* Wk = (const float*)d_in[4];
    const float* Wv = (const float*)d_in[5];
    const float* bq = (const float*)d_in[6];
    const float* bk = (const float*)d_in[7];
    const float* bv = (const float*)d_in[8];
    const float* Wo = (const float*)d_in[9];
    const float* bo = (const float*)d_in[10];
    const float* W1 = (const float*)d_in[11];
    const float* b1 = (const float*)d_in[12];
    const float* W2 = (const float*)d_in[13];
    const float* b2 = (const float*)d_in[14];
    const float* ln1g = (const float*)d_in[15];
    const float* ln1b = (const float*)d_in[16];
    const float* ln2g = (const float*)d_in[17];
    const float* ln2b = (const float*)d_in[18];
    float* out = (float*)d_out;

    // ---- workspace layout, ~174 MB peak ----
    char* base = (char*)d_ws;
    const size_t MB = 1u << 20;
    float* mnorm   = (float*)(base);                    // 128 KB
    float* msc     = (float*)(base + 256*1024);         // 128 KB (Epat row scales)
    float* qsc     = (float*)(base + 512*1024);         // 16 KB  (visit row scales)
    int*   knn_idx = (int*)  (base + 2*MB);             // 160 KB
    float* qh      = (float*)(base + 3*MB);             // 8 MB
    float* attn_o  = qh;                                // alias: qh dead after attn
    float* x1      = (float*)(base + 11*MB);            // 8 MB
    float* ff      = (float*)(base + 19*MB);            // 8 MB
    unsigned short* Qb    = (unsigned short*)(base + 27*MB);  // 4 MB (visit bf16)
    unsigned short* ctx_b = (unsigned short*)(base + 31*MB);  // 4 MB
    unsigned short* x1_b  = (unsigned short*)(base + 35*MB);  // 4 MB
    unsigned short* h1_b  = (unsigned short*)(base + 39*MB);  // 4 MB
    unsigned short* Wq_b  = (unsigned short*)(base + 43*MB);  // 6 x 512 KB
    unsigned short* Wk_b  = Wq_b + 262144;
    unsigned short* Wv_b  = Wk_b + 262144;
    unsigned short* Wo_b  = Wv_b + 262144;
    unsigned short* W1_b  = Wo_b + 262144;
    unsigned short* W2_b  = W1_b + 262144;
    unsigned short* Mb     = (unsigned short*)(base + 46*MB); // 32 MB (Epat bf16)
    unsigned short* Emed_b = (unsigned short*)(base + 78*MB); // 32 MB
    // K|V region (64 MB bf16); cand_part (32 MB) aliases Kall during kNN phase;
    // M8 (16 MB) + Q8 (2 MB) alias Vall (dead until gemm3).
    unsigned short* Kall = (unsigned short*)(base + 110*MB);  // 32 MB
    unsigned short* Vall = Kall + (size_t)NMEM * DD;          // 32 MB
    unsigned* cand_part = (unsigned*)Kall;                    // alias (kNN only)
    signed char* M8 = (signed char*)(base + 142*MB);          // alias Vall[0:16MB)
    signed char* Q8 = (signed char*)(base + 158*MB);          // alias Vall[16:18MB)

    // ---- casts + norms + int8 quant (2 dispatches total) ----
    cast_norm2_kernel<<<dim3(NMEM / 4, 3), 256, 0, stream>>>(
        Epat, Mb, Emed, Emed_b, visit, M8, Q8, mnorm, msc, qsc);
    CastDesc cd;
    cd.in[0] = visit; cd.out[0] = Qb;
    cd.in[1] = Wq; cd.in[2] = Wk; cd.in[3] = Wv; cd.in[4] = Wo; cd.in[5] = W1; cd.in[6] = W2;
    cd.out[1] = Wq_b; cd.out[2] = Wk_b; cd.out[3] = Wv_b; cd.out[4] = Wo_b; cd.out[5] = W1_b; cd.out[6] = W2_b;
    cd.start[0] = 0; cd.start[1] = 2048;
    for (int s = 2; s <= 7; ++s) cd.start[s] = cd.start[s-1] + 256;
    cast_multi_kernel<<<cd.start[7], 256, 0, stream>>>(cd);

    // ---- kNN: int8 MFMA scores (swapped operands) + register-local selection ----
    gemm_knn_kernel<<<dim3(NBX, BQ / 128), 512, 0, stream>>>(Q8, M8, mnorm, msc, qsc, cand_part);
    knn_select_kernel<<<BQ, 256, 0, stream>>>(cand_part, visit, Epat, mnorm, knn_idx);

    // ---- K/V/q projections in one compacted dispatch (Kall write overwrites cand_part;
    //      Vall write overwrites M8/Q8 — both dead by then)
    G3 g3;
    g3.A[0] = Mb;     g3.B[0] = Wk_b; g3.bias[0] = bk; g3.C[0] = Kall; g3.obf[0] = 1;
    g3.A[1] = Emed_b; g3.B[1] = Wv_b; g3.bias[1] = bv; g3.C[1] = Vall; g3.obf[1] = 1;
    g3.A[2] = Qb;     g3.B[2] = Wq_b; g3.bias[2] = bq; g3.C[2] = qh;   g3.obf[2] = 0;
    gemm3_kernel<<<dim3(4, 544), 256, 0, stream>>>(g3);

    attn_kernel<<<BQ, 512, 0, stream>>>(qh, Kall, Vall, knn_idx, ctx_b);

    gemm_bf16_nt<0,0><<<dim3(4, BQ / 128), 256, 0, stream>>>(ctx_b, Wo_b, bo, attn_o, DD);
    add_ln_kernel<1><<<BQ, 256, 0, stream>>>(visit, attn_o, ln1g, ln1b, x1, x1_b);
    gemm_bf16_nt<1,1><<<dim3(4, BQ / 128), 256, 0, stream>>>(x1_b, W1_b, b1, h1_b, DD);
    gemm_bf16_nt<0,0><<<dim3(4, BQ / 128), 256, 0, stream>>>(h1_b, W2_b, b2, ff,   DD);
    add_ln_kernel<0><<<BQ, 256, 0, stream>>>(x1, ff, ln2g, ln2b, out, nullptr);
}